// Round 4
// baseline (51635.065 us; speedup 1.0000x reference)
//
#include <hip/hip_runtime.h>
#include <stdint.h>

// ---------------- constants ----------------
constexpr int kB  = 64;    // batch
constexpr int kT  = 512;   // seq len
constexpr int kHD = 512;   // per-direction hidden
constexpr int kC  = 16;    // classes
constexpr int kL  = 32;    // time-chunk length
constexpr int kSTART = 14;
constexpr int kSTOP  = 15;
#define NEGV (-10000.0f)

typedef __bf16 bf16x8 __attribute__((ext_vector_type(8)));
typedef float  f32x4  __attribute__((ext_vector_type(4)));

union U16x8 { uint4 u; bf16x8 v; };

__device__ __forceinline__ unsigned short f2bf(float f) {
    union { float f; unsigned int u; } x; x.f = f;
    unsigned int u = x.u;
    u += 0x7fffu + ((u >> 16) & 1u);           // RNE
    return (unsigned short)(u >> 16);
}
__device__ __forceinline__ float bf2f(unsigned int hbits) {
    union { unsigned int u; float f; } x; x.u = hbits << 16;
    return x.f;
}

typedef __attribute__((address_space(1))) const unsigned int GASU;
typedef __attribute__((address_space(3))) unsigned int LASU;
__device__ __forceinline__ void ld_lds16(const unsigned short* g, unsigned short* l) {
    __builtin_amdgcn_global_load_lds((GASU*)g, (LASU*)l, 16, 0, 0);
}

// ---------------- plain f32 -> bf16 cast (Wh weights) ----------------
__global__ void k_cast(const float* __restrict__ src, unsigned short* __restrict__ dst, int n8) {
    int i = blockIdx.x * 256 + threadIdx.x;
    if (i >= n8) return;
    const float4* s = (const float4*)(src + (size_t)i * 8);
    float4 a = s[0], b = s[1];
    ushort4 lo, hi;
    lo.x = f2bf(a.x); lo.y = f2bf(a.y); lo.z = f2bf(a.z); lo.w = f2bf(a.w);
    hi.x = f2bf(b.x); hi.y = f2bf(b.y); hi.z = f2bf(b.z); hi.w = f2bf(b.w);
    ushort4* d = (ushort4*)(dst + (size_t)i * 8);
    d[0] = lo; d[1] = hi;
}

// ---------------- permuting cast for Wx: dst row d*2048 + col*4 + gate = src row d*2048 + gate*512 + col
__global__ void k_castWx(const float* __restrict__ src, unsigned short* __restrict__ dst, int K) {
    int np = blockIdx.x;               // 0..4095 dst row
    int dd = np >> 11, r = np & 2047;
    int g = r & 3, cj = r >> 2;
    const float* s = src + ((size_t)(dd * 2048 + g * 512 + cj)) * K;
    unsigned short* d = dst + (size_t)np * K;
    for (int e = threadIdx.x * 8; e < K; e += 128 * 8) {   // block = 128
        float4 a = *(const float4*)(s + e);
        float4 b = *(const float4*)(s + e + 4);
        ushort4 lo, hi;
        lo.x = f2bf(a.x); lo.y = f2bf(a.y); lo.z = f2bf(a.z); lo.w = f2bf(a.w);
        hi.x = f2bf(b.x); hi.y = f2bf(b.y); hi.z = f2bf(b.z); hi.w = f2bf(b.w);
        *(ushort4*)(d + e) = lo; *(ushort4*)(d + e + 4) = hi;
    }
}

// ---------------- embedding gather: X0[t*64+b][e] = bf16(emb[sent[b][t]][e]) ----------------
__global__ void k_embed(const int* __restrict__ sent, const float* __restrict__ emb,
                        unsigned short* __restrict__ X0) {
    int row = blockIdx.x;              // t*64 + b
    int t = row >> 6, b = row & 63;
    int v = sent[b * kT + t];
    const float4* src = (const float4*)(emb + (size_t)v * 512);
    float4 f = src[threadIdx.x];       // block = 128 -> 512 floats
    ushort4 o;
    o.x = f2bf(f.x); o.y = f2bf(f.y); o.z = f2bf(f.z); o.w = f2bf(f.w);
    ((ushort4*)(X0 + (size_t)row * 512))[threadIdx.x] = o;
}

// ---------------- init: h/c states, permuted fused biases, barrier counters ----------------
// hcur (per layer): [parity][dir][64][512] bf16 ; ccur: [layer][dir][64][512] f32
__global__ void k_init(const float* __restrict__ h0, const float* __restrict__ c0,
                       const float* __restrict__ bih0, const float* __restrict__ bhh0,
                       const float* __restrict__ bih1, const float* __restrict__ bhh1,
                       unsigned short* __restrict__ hcur, float* __restrict__ ccur,
                       float* __restrict__ biascat0, float* __restrict__ biascat1,
                       unsigned int* __restrict__ bar) {
    int i = blockIdx.x * blockDim.x + threadIdx.x;
    const int NS = 4 * kB * kHD;       // 131072
    if (i < NS) {
        int l = i >> 16;               // layer
        int rem = i & 65535;           // d*32768 + b*512 + j
        hcur[(size_t)l * 131072 + rem] = f2bf(h0[i]);   // parity-0 region
        ccur[i] = c0[i];
    } else if (i < NS + 8192) {
        int j2 = i - NS;
        int l = j2 >> 12;
        int n = j2 & 4095;             // src index: d*2048 + g*512 + col
        int dd = n >> 11, r = n & 2047;
        int g = r >> 9, cj = r & 511;
        float v = l ? (bih1[n] + bhh1[n]) : (bih0[n] + bhh0[n]);
        int np = dd * 2048 + cj * 4 + g;   // permuted (gate-interleaved)
        (l ? biascat1 : biascat0)[np] = v;
    } else if (i < NS + 8192 + 16) {
        bar[i - NS - 8192] = 0u;
    }
}

// ---------------- chunk GEMM: Gx[g][n] = bf16( A[arow(g)][:] . B[n][:] + bias[n] ) --------
// Gx chunk: rows 0..2047 = fwd window (A row = afwd + g), rows 2048..4095 = bwd window
// (A row = abwd + g - 2048). 128x128 tiles, BK=32, global_load_lds staging. grid = 32*32.
__launch_bounds__(256, 2)
__global__ void k_gemm(const unsigned short* __restrict__ A,
                       const unsigned short* __restrict__ Bm,
                       const float* __restrict__ bias,
                       unsigned short* __restrict__ Cm,
                       int K, int afwd, int abwd) {
    const int nb = blockIdx.x & 31;
    const int mb = blockIdx.x >> 5;                  // 0..31
    const int m0w = mb << 7;                         // Gx row base
    const int arow0 = (m0w < 2048) ? (afwd + m0w) : (abwd + (m0w - 2048));
    const int n0 = nb << 7;
    const int tid = threadIdx.x;
    const int lane = tid & 63;
    const int wave = tid >> 6;
    const int wm = wave >> 1, wn = wave & 1;
    const int l16 = lane & 15, quad = lane >> 4;
    __shared__ unsigned short As[128 * 32];
    __shared__ unsigned short Bs[128 * 32];
    const int srw = wave * 32 + (lane >> 2);         // staging row (first half)
    const int sc  = lane & 3;                        // 8-short col-chunk
    unsigned short* AsW0 = As + wave * 1024;
    unsigned short* AsW1 = As + wave * 1024 + 512;
    unsigned short* BsW0 = Bs + wave * 1024;
    unsigned short* BsW1 = Bs + wave * 1024 + 512;

    f32x4 acc[4][4];
    #pragma unroll
    for (int i = 0; i < 4; ++i)
        #pragma unroll
        for (int jj = 0; jj < 4; ++jj) acc[i][jj] = (f32x4){0,0,0,0};

    const int kiters = K >> 5;
    for (int kk = 0; kk < kiters; ++kk) {
        __syncthreads();
        ld_lds16(A  + (size_t)(arow0 + srw)      * K + kk * 32 + sc * 8, AsW0);
        ld_lds16(A  + (size_t)(arow0 + srw + 16) * K + kk * 32 + sc * 8, AsW1);
        ld_lds16(Bm + (size_t)(n0 + srw)         * K + kk * 32 + sc * 8, BsW0);
        ld_lds16(Bm + (size_t)(n0 + srw + 16)    * K + kk * 32 + sc * 8, BsW1);
        __syncthreads();
        U16x8 af[4], bf[4];
        #pragma unroll
        for (int i = 0; i < 4; ++i) {
            af[i].u = *(const uint4*)(As + (wm * 64 + i * 16 + l16) * 32 + quad * 8);
            bf[i].u = *(const uint4*)(Bs + (wn * 64 + i * 16 + l16) * 32 + quad * 8);
        }
        #pragma unroll
        for (int i = 0; i < 4; ++i)
            #pragma unroll
            for (int jj = 0; jj < 4; ++jj)
                acc[i][jj] = __builtin_amdgcn_mfma_f32_16x16x32_bf16(af[i].v, bf[jj].v, acc[i][jj], 0, 0, 0);
    }
    // epilogue: + bias, bf16 store. C/D layout: col=l16, row=quad*4+rr (verified m89)
    #pragma unroll
    for (int jj = 0; jj < 4; ++jj) {
        int n = n0 + wn * 64 + jj * 16 + l16;
        float bv = bias[n];
        #pragma unroll
        for (int i = 0; i < 4; ++i) {
            int mrow = m0w + wm * 64 + i * 16 + quad * 4;
            #pragma unroll
            for (int rr = 0; rr < 4; ++rr)
                Cm[(size_t)(mrow + rr) * 4096 + n] = f2bf(acc[i][jj][rr] + bv);
        }
    }
}

// ---------------- recurrence chunk: kL steps, G = h.Wh^T + Gx; K=512, Wh in VGPRs --------
// grid = 256 WGs: d = blk>>7, bq = (blk>>5)&3, js = blk&31. block 256 = 4 waves (= gates).
// Barrier groups (d,bq): 32 WGs. split!=0 -> layer1 write routing (S side-buffer).
__launch_bounds__(256, 1)
__global__ void k_rec(const unsigned short* __restrict__ Wh,   // [2][2048][512] bf16 (gate-major)
                      const unsigned short* __restrict__ Gx,    // [4096][4096] bf16 chunk
                      unsigned short* __restrict__ hcur,        // [par][dir][64][512] bf16
                      float* __restrict__ cc,                   // [dir][64][512] f32
                      unsigned short* __restrict__ hs,          // HS [512*64][1024] bf16
                      unsigned short* __restrict__ S,           // [512*64][512] side buffer
                      unsigned int* __restrict__ bar,           // [8]
                      int s0, int split) {
    const int blk = blockIdx.x;
    const int d  = blk >> 7;
    const int bq = (blk >> 5) & 3;
    const int j0 = (blk & 31) << 4;
    const int b0 = bq << 4;
    const int tid = threadIdx.x;
    const int wave = tid >> 6;         // gate: 0=i 1=f 2=g 3=o
    const int lane = tid & 63;
    const int l16 = lane & 15;
    const int quad = lane >> 4;

    __shared__ unsigned short zbuf[16 * 512];      // 16 batch rows x 512 k, XOR-swizzled blocks
    __shared__ float gstash[4][16][17];

    // Wh fragments in VGPRs for the whole chunk: 16 x uint4 = 64 VGPRs
    uint4 wreg[16];
    {
        const unsigned short* wrow = Wh + ((size_t)d * 2048 + wave * 512 + j0 + l16) * 512 + quad * 8;
        #pragma unroll
        for (int kk = 0; kk < 16; ++kk) wreg[kk] = *(const uint4*)(wrow + kk * 32);
    }
    const int m = tid >> 4;            // batch row within quarter
    const int j = tid & 15;            // col within slice
    float creg = cc[((size_t)d * 64 + b0 + m) * 512 + j0 + j];

    const int sr = tid >> 4;           // staging row
    const int sp = tid & 15;           // staging 32-short chunk
    unsigned int* barg = bar + (d * 4 + bq);
    const int base_rounds = (s0 >> 5) * (kL - 1);

    for (int sl = 0; sl < kL; ++sl) {
        const int s = s0 + sl;
        const int t = d ? (kT - 1 - s) : s;
        const int grow = d ? (2048 + (kL - 1 - sl) * 64 + b0 + m) : (sl * 64 + b0 + m);
        ushort4 gx4 = *(const ushort4*)(Gx + (size_t)grow * 4096 + d * 2048 + (j0 + j) * 4);
        // stage h (prev step) into LDS, XOR-swizzled: block cb stored at cb ^ (row&7)
        {
            const unsigned short* hread = hcur + ((size_t)((s & 1) * 2 + d) * 64) * 512;
            const uint4* src = (const uint4*)(hread + (size_t)(b0 + sr) * 512 + sp * 32);
            #pragma unroll
            for (int i = 0; i < 4; ++i) {
                int pb = (sp * 4 + i) ^ (sr & 7);
                *(uint4*)(zbuf + sr * 512 + pb * 8) = src[i];
            }
        }
        __syncthreads();
        f32x4 acc = {0, 0, 0, 0};
        #pragma unroll
        for (int kk = 0; kk < 16; ++kk) {
            int pb = (kk * 4 + quad) ^ (l16 & 7);
            U16x8 a; a.u = *(const uint4*)(zbuf + l16 * 512 + pb * 8);
            U16x8 b; b.u = wreg[kk];
            acc = __builtin_amdgcn_mfma_f32_16x16x32_bf16(a.v, b.v, acc, 0, 0, 0);
        }
        #pragma unroll
        for (int rr = 0; rr < 4; ++rr) gstash[wave][quad * 4 + rr][l16] = acc[rr];
        __syncthreads();
        // cell update (c in register)
        {
            float gi = gstash[0][m][j] + bf2f(gx4.x);
            float gf = gstash[1][m][j] + bf2f(gx4.y);
            float gg = gstash[2][m][j] + bf2f(gx4.z);
            float go = gstash[3][m][j] + bf2f(gx4.w);
            float si = 1.f / (1.f + __expf(-gi));
            float sf = 1.f / (1.f + __expf(-gf));
            float so = 1.f / (1.f + __expf(-go));
            float tg = tanhf(gg);
            float cn = sf * creg + si * tg;
            creg = cn;
            float hn = so * tanhf(cn);
            unsigned short hb = f2bf(hn);
            unsigned short* hwrite = hcur + ((size_t)(((s + 1) & 1) * 2 + d) * 64) * 512;
            hwrite[(size_t)(b0 + m) * 512 + j0 + j] = hb;
            // output routing: layer0 -> HS in place; layer1 -> early half to S
            bool toS = split && (d ? (t >= 256) : (t < 256));
            if (toS)
                S[((size_t)t * 64 + b0 + m) * 512 + j0 + j] = hb;
            else
                hs[((size_t)t * 64 + b0 + m) * 1024 + (size_t)d * 512 + j0 + j] = hb;
        }
        __syncthreads();   // protect zbuf for next step until all waves' MFMA reads done
        // per-(dir,quarter) device barrier over 32 WGs (skip at chunk end)
        if (sl + 1 < kL) {
            __threadfence();
            if (tid == 0) {
                __hip_atomic_fetch_add(barg, 1u, __ATOMIC_ACQ_REL, __HIP_MEMORY_SCOPE_AGENT);
                unsigned tgt = (unsigned)(base_rounds + sl + 1) * 32u;
                while (__hip_atomic_load(barg, __ATOMIC_ACQUIRE, __HIP_MEMORY_SCOPE_AGENT) < tgt)
                    __builtin_amdgcn_s_sleep(1);
            }
            __syncthreads();
            __threadfence();
        }
    }
    cc[((size_t)d * 64 + b0 + m) * 512 + j0 + j] = creg;
}

// ---------------- final linear (reassembles h from HS / S) ----------------
__global__ void k_linear(const unsigned short* __restrict__ hs1,
                         const unsigned short* __restrict__ S,
                         const float* __restrict__ lw, const float* __restrict__ lb,
                         float* __restrict__ feats) {
    int p = blockIdx.x * 4 + (threadIdx.x >> 6);   // row = t*64+b
    int lane = threadIdx.x & 63;
    int t = p >> 6, b = p & 63;
    int col = lane * 16;
    bool hfHalf = col < 512;
    bool useS = hfHalf ? (t < 256) : (t >= 256);
    const unsigned short* rowp = useS
        ? (S + ((size_t)t * 64 + b) * 512 + (col & 511))
        : (hs1 + (size_t)p * 1024 + col);
    uint4 u0 = ((const uint4*)rowp)[0];
    uint4 u1 = ((const uint4*)rowp)[1];
    unsigned int uu[8] = {u0.x, u0.y, u0.z, u0.w, u1.x, u1.y, u1.z, u1.w};
    float x[16];
    #pragma unroll
    for (int i = 0; i < 8; ++i) { x[2*i] = bf2f(uu[i] & 0xffffu); x[2*i+1] = bf2f(uu[i] >> 16); }
    float acc[16];
    #pragma unroll
    for (int c = 0; c < 16; ++c) {
        const float4* w4 = (const float4*)(lw + (size_t)c * 1024 + col);
        float a = 0.f;
        #pragma unroll
        for (int k4 = 0; k4 < 4; ++k4) {
            float4 w = w4[k4];
            a += x[k4*4+0]*w.x + x[k4*4+1]*w.y + x[k4*4+2]*w.z + x[k4*4+3]*w.w;
        }
        acc[c] = a;
    }
    #pragma unroll
    for (int c = 0; c < 16; ++c) {
        #pragma unroll
        for (int off = 32; off; off >>= 1) acc[c] += __shfl_xor(acc[c], off, 64);
    }
    if (lane == 0) {
        float* o = feats + (size_t)b * (kT * kC) + t * kC;
        #pragma unroll
        for (int c = 0; c < 16; ++c) o[c] = acc[c] + lb[c];
    }
}

// ---------------- Viterbi: one wave per batch element ----------------
__global__ void k_viterbi(const float* __restrict__ feats, const float* __restrict__ trans,
                          float* __restrict__ out) {
    int b = blockIdx.x;
    int lane = threadIdx.x;            // block = 64
    __shared__ unsigned char bp[kT * kC];
    __shared__ float fv[2][kC];
    __shared__ float tbuf[kC];
    float trow[16];
    float tstop = 0.f;
    if (lane < 16) {
        #pragma unroll
        for (int p = 0; p < 16; ++p) trow[p] = trans[lane * 16 + p];
        tstop = trans[kSTOP * 16 + lane];
        fv[0][lane] = (lane == kSTART) ? 0.f : NEGV;
    }
    __syncthreads();
    const float* fb = feats + (size_t)b * (kT * kC);
    for (int t = 0; t < kT; ++t) {
        if (lane < 16) {
            float m = -3.4e38f; int arg = 0;
            #pragma unroll
            for (int p = 0; p < 16; ++p) {
                float v = fv[t & 1][p] + trow[p];
                if (v > m) { m = v; arg = p; }   // strict > : first max, matches jnp.argmax
            }
            bp[t * 16 + lane] = (unsigned char)arg;
            fv[(t + 1) & 1][lane] = m + fb[t * 16 + lane];
        }
        __syncthreads();
    }
    if (lane < 16) tbuf[lane] = fv[kT & 1][lane] + tstop;
    __syncthreads();
    if (lane == 0) {
        float bm = tbuf[0]; int best = 0;
        #pragma unroll
        for (int p = 1; p < 16; ++p) if (tbuf[p] > bm) { bm = tbuf[p]; best = p; }
        out[b] = bm;
        float* path = out + kB + (size_t)b * kT;
        int tag = best;
        for (int t = kT - 1; t >= 0; --t) {
            path[t] = (float)tag;
            tag = bp[t * 16 + tag];
        }
    }
}

// ---------------- host ----------------
extern "C" void kernel_launch(void* const* d_in, const int* in_sizes, int n_in,
                              void* d_out, int out_size, void* d_ws, size_t ws_size,
                              hipStream_t stream) {
    const int*   sent = (const int*)d_in[0];
    const float* emb  = (const float*)d_in[1];
    const float* wih0 = (const float*)d_in[2];
    const float* whh0 = (const float*)d_in[3];
    const float* bih0 = (const float*)d_in[4];
    const float* bhh0 = (const float*)d_in[5];
    const float* wih1 = (const float*)d_in[6];
    const float* whh1 = (const float*)d_in[7];
    const float* bih1 = (const float*)d_in[8];
    const float* bhh1 = (const float*)d_in[9];
    const float* lw   = (const float*)d_in[10];
    const float* lb   = (const float*)d_in[11];
    const float* tr   = (const float*)d_in[12];
    const float* h0   = (const float*)d_in[13];
    const float* c0   = (const float*)d_in[14];
    float* out = (float*)d_out;

    char* ws = (char*)d_ws;
    size_t off = 0;
    auto alloc = [&](size_t bytes) -> void* {
        void* p = ws + off; off += (bytes + 255) & ~(size_t)255; return p;
    };
    // X0 (32MB) + Wx0 (4MB) are dead during layer-1 recurrence; S (33.5MB) aliases them.
    unsigned short* X0    = (unsigned short*)alloc((size_t)kT * kB * 512 * 2);       // 32MB
    unsigned short* Wx0   = (unsigned short*)alloc((size_t)4096 * 512 * 2);          // 4MB
    unsigned short* S     = (unsigned short*)X0;                                     // alias
    unsigned short* Wh0   = (unsigned short*)alloc((size_t)4096 * 512 * 2);          // 4MB
    unsigned short* Wx1   = (unsigned short*)alloc((size_t)4096 * 1024 * 2);         // 8MB
    unsigned short* Wh1   = (unsigned short*)alloc((size_t)4096 * 512 * 2);          // 4MB
    float*          biascat0 = (float*)alloc(4096 * 4);
    float*          biascat1 = (float*)alloc(4096 * 4);
    unsigned short* HS    = (unsigned short*)alloc((size_t)kT * kB * 1024 * 2);      // 67MB (hs0 == hs1)
    unsigned short* hcur  = (unsigned short*)alloc((size_t)2 * 2 * 2 * kB * kHD * 2);// [l][p][d][B][HD]
    float*          ccur  = (float*)alloc((size_t)4 * kB * kHD * 4);                 // [l][d][B][HD]
    float*          feats = (float*)alloc((size_t)kB * kT * kC * 4);
    unsigned int*   bar   = (unsigned int*)alloc(16 * 4);
    unsigned short* Gx    = (unsigned short*)alloc((size_t)4096 * 4096 * 2);         // 33.5MB chunk

    k_castWx<<<4096, 128, 0, stream>>>(wih0, Wx0, 512);
    k_cast  <<<(4096 * 512 / 8 + 255) / 256, 256, 0, stream>>>(whh0, Wh0, 4096 * 512 / 8);
    k_castWx<<<4096, 128, 0, stream>>>(wih1, Wx1, 1024);
    k_cast  <<<(4096 * 512 / 8 + 255) / 256, 256, 0, stream>>>(whh1, Wh1, 4096 * 512 / 8);
    k_init<<<(4 * kB * kHD + 8192 + 16 + 255) / 256, 256, 0, stream>>>(
        h0, c0, bih0, bhh0, bih1, bhh1, hcur, ccur, biascat0, biascat1, bar);
    k_embed<<<kT * kB, 128, 0, stream>>>(sent, emb, X0);

    unsigned short* hcur1 = hcur + (size_t)131072;
    float*          ccur1 = ccur + (size_t)65536;

    // layer 0: chunked Gx GEMM (K=512) + recurrence; output -> HS (full rows)
    for (int ch = 0; ch < kT / kL; ++ch) {
        int s0 = ch * kL;
        k_gemm<<<32 * 32, 256, 0, stream>>>(X0, Wx0, biascat0, Gx, 512,
                                            s0 * 64, (kT - kL - s0) * 64);
        k_rec <<<256, 256, 0, stream>>>(Wh0, Gx, hcur, ccur, HS, S, bar, s0, 0);
    }
    // layer 1: chunked Gx GEMM (K=1024, reads HS windows before rec overwrites them)
    for (int ch = 0; ch < kT / kL; ++ch) {
        int s0 = ch * kL;
        k_gemm<<<32 * 32, 256, 0, stream>>>(HS, Wx1, biascat1, Gx, 1024,
                                            s0 * 64, (kT - kL - s0) * 64);
        k_rec <<<256, 256, 0, stream>>>(Wh1, Gx, hcur1, ccur1, HS, S, bar + 8, s0, 1);
    }

    k_linear<<<kT * kB / 4, 256, 0, stream>>>(HS, S, lw, lb, feats);
    k_viterbi<<<kB, 64, 0, stream>>>(feats, tr, out);
}

// Round 5
// 10722.543 us; speedup vs baseline: 4.8156x; 4.8156x over previous
//
#include <hip/hip_runtime.h>
#include <stdint.h>

// ---------------- constants ----------------
constexpr int kB  = 64;    // batch
constexpr int kT  = 512;   // seq len
constexpr int kHD = 512;   // per-direction hidden
constexpr int kC  = 16;    // classes
constexpr int kL  = 32;    // time-chunk length
constexpr int kSTART = 14;
constexpr int kSTOP  = 15;
#define NEGV (-10000.0f)

typedef __bf16 bf16x8 __attribute__((ext_vector_type(8)));
typedef float  f32x4  __attribute__((ext_vector_type(4)));

union U16x8 { uint4 u; bf16x8 v; };

__device__ __forceinline__ unsigned short f2bf(float f) {
    union { float f; unsigned int u; } x; x.f = f;
    unsigned int u = x.u;
    u += 0x7fffu + ((u >> 16) & 1u);           // RNE
    return (unsigned short)(u >> 16);
}
__device__ __forceinline__ float bf2f(unsigned int hbits) {
    union { unsigned int u; float f; } x; x.u = hbits << 16;
    return x.f;
}

typedef __attribute__((address_space(1))) const unsigned int GASU;
typedef __attribute__((address_space(3))) unsigned int LASU;
__device__ __forceinline__ void ld_lds16(const unsigned short* g, unsigned short* l) {
    __builtin_amdgcn_global_load_lds((GASU*)g, (LASU*)l, 16, 0, 0);
}

// ---------------- permuting cast: dst row d*2048 + col*4 + gate = src row d*2048 + gate*512 + col
__global__ void k_castWx(const float* __restrict__ src, unsigned short* __restrict__ dst, int K) {
    int np = blockIdx.x;               // 0..4095 dst row
    int dd = np >> 11, r = np & 2047;
    int g = r & 3, cj = r >> 2;
    const float* s = src + ((size_t)(dd * 2048 + g * 512 + cj)) * K;
    unsigned short* d = dst + (size_t)np * K;
    for (int e = threadIdx.x * 8; e < K; e += 128 * 8) {   // block = 128
        float4 a = *(const float4*)(s + e);
        float4 b = *(const float4*)(s + e + 4);
        ushort4 lo, hi;
        lo.x = f2bf(a.x); lo.y = f2bf(a.y); lo.z = f2bf(a.z); lo.w = f2bf(a.w);
        hi.x = f2bf(b.x); hi.y = f2bf(b.y); hi.z = f2bf(b.z); hi.w = f2bf(b.w);
        *(ushort4*)(d + e) = lo; *(ushort4*)(d + e + 4) = hi;
    }
}

// ---------------- embedding gather ----------------
__global__ void k_embed(const int* __restrict__ sent, const float* __restrict__ emb,
                        unsigned short* __restrict__ X0) {
    int row = blockIdx.x;              // t*64 + b
    int t = row >> 6, b = row & 63;
    int v = sent[b * kT + t];
    const float4* src = (const float4*)(emb + (size_t)v * 512);
    float4 f = src[threadIdx.x];       // block = 128
    ushort4 o;
    o.x = f2bf(f.x); o.y = f2bf(f.y); o.z = f2bf(f.z); o.w = f2bf(f.w);
    ((ushort4*)(X0 + (size_t)row * 512))[threadIdx.x] = o;
}

// ---------------- init: h/c states, permuted fused biases, flags ----------------
__global__ void k_init(const float* __restrict__ h0, const float* __restrict__ c0,
                       const float* __restrict__ bih0, const float* __restrict__ bhh0,
                       const float* __restrict__ bih1, const float* __restrict__ bhh1,
                       unsigned short* __restrict__ hcur, float* __restrict__ ccur,
                       float* __restrict__ biascat0, float* __restrict__ biascat1,
                       unsigned int* __restrict__ flags) {
    int i = blockIdx.x * blockDim.x + threadIdx.x;
    const int NS = 4 * kB * kHD;       // 131072
    if (i < NS) {
        int l = i >> 16;
        int rem = i & 65535;           // d*32768 + b*512 + j
        hcur[(size_t)l * 131072 + rem] = f2bf(h0[i]);   // parity-0 region
        ccur[i] = c0[i];
    } else if (i < NS + 8192) {
        int j2 = i - NS;
        int l = j2 >> 12;
        int n = j2 & 4095;             // src: d*2048 + g*512 + col
        int dd = n >> 11, r = n & 2047;
        int g = r >> 9, cj = r & 511;
        float v = l ? (bih1[n] + bhh1[n]) : (bih0[n] + bhh0[n]);
        int np = dd * 2048 + cj * 4 + g;   // gate-interleaved
        (l ? biascat1 : biascat0)[np] = v;
    } else if (i < NS + 8192 + 256) {
        flags[i - NS - 8192] = 0u;
    }
}

// ---------------- chunk GEMM (unchanged from R4, staging-fixed) ----------------
__launch_bounds__(256, 2)
__global__ void k_gemm(const unsigned short* __restrict__ A,
                       const unsigned short* __restrict__ Bm,
                       const float* __restrict__ bias,
                       unsigned short* __restrict__ Cm,
                       int K, int afwd, int abwd) {
    const int nb = blockIdx.x & 31;
    const int mb = blockIdx.x >> 5;
    const int m0w = mb << 7;
    const int arow0 = (m0w < 2048) ? (afwd + m0w) : (abwd + (m0w - 2048));
    const int n0 = nb << 7;
    const int tid = threadIdx.x;
    const int lane = tid & 63;
    const int wave = tid >> 6;
    const int wm = wave >> 1, wn = wave & 1;
    const int l16 = lane & 15, quad = lane >> 4;
    __shared__ unsigned short As[128 * 32];
    __shared__ unsigned short Bs[128 * 32];
    const int srw = wave * 32 + (lane >> 2);
    const int sc  = lane & 3;
    unsigned short* AsW0 = As + wave * 1024;
    unsigned short* AsW1 = As + wave * 1024 + 512;
    unsigned short* BsW0 = Bs + wave * 1024;
    unsigned short* BsW1 = Bs + wave * 1024 + 512;

    f32x4 acc[4][4];
    #pragma unroll
    for (int i = 0; i < 4; ++i)
        #pragma unroll
        for (int jj = 0; jj < 4; ++jj) acc[i][jj] = (f32x4){0,0,0,0};

    const int kiters = K >> 5;
    for (int kk = 0; kk < kiters; ++kk) {
        __syncthreads();
        ld_lds16(A  + (size_t)(arow0 + srw)      * K + kk * 32 + sc * 8, AsW0);
        ld_lds16(A  + (size_t)(arow0 + srw + 16) * K + kk * 32 + sc * 8, AsW1);
        ld_lds16(Bm + (size_t)(n0 + srw)         * K + kk * 32 + sc * 8, BsW0);
        ld_lds16(Bm + (size_t)(n0 + srw + 16)    * K + kk * 32 + sc * 8, BsW1);
        __syncthreads();
        U16x8 af[4], bf[4];
        #pragma unroll
        for (int i = 0; i < 4; ++i) {
            af[i].u = *(const uint4*)(As + (wm * 64 + i * 16 + l16) * 32 + quad * 8);
            bf[i].u = *(const uint4*)(Bs + (wn * 64 + i * 16 + l16) * 32 + quad * 8);
        }
        #pragma unroll
        for (int i = 0; i < 4; ++i)
            #pragma unroll
            for (int jj = 0; jj < 4; ++jj)
                acc[i][jj] = __builtin_amdgcn_mfma_f32_16x16x32_bf16(af[i].v, bf[jj].v, acc[i][jj], 0, 0, 0);
    }
    #pragma unroll
    for (int jj = 0; jj < 4; ++jj) {
        int n = n0 + wn * 64 + jj * 16 + l16;
        float bv = bias[n];
        #pragma unroll
        for (int i = 0; i < 4; ++i) {
            int mrow = m0w + wm * 64 + i * 16 + quad * 4;
            #pragma unroll
            for (int rr = 0; rr < 4; ++rr)
                Cm[(size_t)(mrow + rr) * 4096 + n] = f2bf(acc[i][jj][rr] + bv);
        }
    }
}

// ---------------- recurrence chunk v2: hidden-col partitioning, flag barrier (no RMW) ----
// 64 WGs x 512 thr (8 waves). blk: d = blk>>5, bh = (blk>>4)&1 (batch half), wc = blk&15
// (32-col slice -> 128 gate rows of gate-interleaved Wh, held in VGPRs).
// Group (d,bh) = 16 WGs; per-WG step flag, release-store / relaxed-spin + acquire fence.
__launch_bounds__(512, 1)
__global__ void k_rec(const unsigned short* __restrict__ Wh,   // [2][2048][512] bf16 PERMUTED
                      const unsigned short* __restrict__ Gx,    // [4096][4096] bf16 chunk
                      unsigned short* __restrict__ hcur,        // [par][dir][64][512] bf16
                      float* __restrict__ cc,                   // [dir][64][512] f32
                      unsigned short* __restrict__ hs,          // HS [512*64][1024]
                      unsigned short* __restrict__ S,           // side buffer [512*64][512]
                      unsigned int* __restrict__ flags,         // [4][16]
                      int s0, int split) {
    const int blk = blockIdx.x;
    const int d  = blk >> 5;
    const int bh = (blk >> 4) & 1;
    const int wc = blk & 15;
    const int tid = threadIdx.x;
    const int wave = tid >> 6;         // 0..7
    const int lane = tid & 63;
    const int l16 = lane & 15;
    const int quad = lane >> 4;

    __shared__ unsigned short zbuf[32 * 520];      // 32 batch rows x 512 k, +8 pad
    __shared__ float gstash[8][16][17];
    __shared__ unsigned short hstash[32 * 32];

    // Wh fragments: wave covers gate rows [wc*128 + wave*16, +16)
    uint4 wreg[16];
    {
        const unsigned short* wrow =
            Wh + ((size_t)d * 2048 + wc * 128 + wave * 16 + l16) * 512 + quad * 8;
        #pragma unroll
        for (int kk = 0; kk < 16; ++kk) wreg[kk] = *(const uint4*)(wrow + kk * 32);
    }
    // cell ownership: thread -> (m16 = tid>>5, j = tid&31), rounds mt = 0,1
    const int m16 = tid >> 5;
    const int j   = tid & 31;
    float cst[2];
    #pragma unroll
    for (int mt = 0; mt < 2; ++mt)
        cst[mt] = cc[((size_t)d * 64 + bh * 32 + mt * 16 + m16) * 512 + wc * 32 + j];

    unsigned int* flg = flags + (d * 2 + bh) * 16;
    const int sr   = tid >> 4;          // staging row 0..31
    const int scol = (tid & 15) * 32;   // staging col (shorts)

    for (int sl = 0; sl < kL; ++sl) {
        const int s = s0 + sl;
        const int t = d ? (kT - 1 - s) : s;
        // wait for all 16 group peers to have completed step s-1 (covers RAW and WAR)
        if (sl > 0) {
            if (tid == 0) {
                unsigned tgt = (unsigned)s;
                for (;;) {
                    bool ok = true;
                    #pragma unroll
                    for (int p = 0; p < 16; ++p)
                        ok &= (__hip_atomic_load(flg + p, __ATOMIC_RELAXED,
                                                 __HIP_MEMORY_SCOPE_AGENT) >= tgt);
                    if (ok) break;
                    __builtin_amdgcn_s_sleep(1);
                }
            }
            __syncthreads();
            __builtin_amdgcn_fence(__ATOMIC_ACQUIRE, "agent");
        }
        // stage h half (32 x 512) into padded LDS; rows offset by 4 banks -> ~2-way
        {
            const unsigned short* hread = hcur + ((size_t)((s & 1) * 2 + d) * 64) * 512;
            const uint4* src = (const uint4*)(hread + (size_t)(bh * 32 + sr) * 512 + scol);
            uint4* dst = (uint4*)(zbuf + sr * 520 + scol);
            dst[0] = src[0]; dst[1] = src[1]; dst[2] = src[2]; dst[3] = src[3];
        }
        __syncthreads();
        f32x4 acc[2];
        acc[0] = (f32x4){0, 0, 0, 0};
        acc[1] = (f32x4){0, 0, 0, 0};
        #pragma unroll
        for (int kk = 0; kk < 16; ++kk) {
            U16x8 b; b.u = wreg[kk];
            #pragma unroll
            for (int mt = 0; mt < 2; ++mt) {
                U16x8 a; a.u = *(const uint4*)(zbuf + (mt * 16 + l16) * 520 + kk * 32 + quad * 8);
                acc[mt] = __builtin_amdgcn_mfma_f32_16x16x32_bf16(a.v, b.v, acc[mt], 0, 0, 0);
            }
        }
        // update rounds (gstash reused per mt)
        #pragma unroll
        for (int mt = 0; mt < 2; ++mt) {
            __syncthreads();
            #pragma unroll
            for (int rr = 0; rr < 4; ++rr) gstash[wave][quad * 4 + rr][l16] = acc[mt][rr];
            __syncthreads();
            int b = bh * 32 + mt * 16 + m16;
            int grow = d ? (2048 + (kL - 1 - sl) * 64 + b) : (sl * 64 + b);
            ushort4 gx4 = *(const ushort4*)(Gx + (size_t)grow * 4096 + d * 2048 + (wc * 32 + j) * 4);
            float gi = gstash[j >> 2][m16][(j & 3) * 4 + 0] + bf2f(gx4.x);
            float gf = gstash[j >> 2][m16][(j & 3) * 4 + 1] + bf2f(gx4.y);
            float gg = gstash[j >> 2][m16][(j & 3) * 4 + 2] + bf2f(gx4.z);
            float go = gstash[j >> 2][m16][(j & 3) * 4 + 3] + bf2f(gx4.w);
            float si = 1.f / (1.f + __expf(-gi));
            float sf = 1.f / (1.f + __expf(-gf));
            float so = 1.f / (1.f + __expf(-go));
            float tg = tanhf(gg);
            float cn = sf * cst[mt] + si * tg;
            cst[mt] = cn;
            float hn = so * tanhf(cn);
            hstash[(mt * 16 + m16) * 32 + j] = f2bf(hn);
        }
        __syncthreads();
        // write out h slice + hs/S (coalesced 64B runs per row)
        {
            int r = tid >> 4, c2 = (tid & 15) * 2;
            unsigned int v = *(const unsigned int*)(hstash + r * 32 + c2);
            unsigned short* hwrite = hcur + ((size_t)(((s + 1) & 1) * 2 + d) * 64) * 512;
            *(unsigned int*)(hwrite + (size_t)(bh * 32 + r) * 512 + wc * 32 + c2) = v;
            int b = bh * 32 + r;
            bool toS = split && (d ? (t >= 256) : (t < 256));
            if (toS)
                *(unsigned int*)(S + ((size_t)t * 64 + b) * 512 + wc * 32 + c2) = v;
            else
                *(unsigned int*)(hs + ((size_t)t * 64 + b) * 1024 + (size_t)d * 512 + wc * 32 + c2) = v;
        }
        __syncthreads();   // drains each wave's vmcnt -> stores are in L2
        if (sl + 1 < kL && tid == 0)
            __hip_atomic_store(flg + wc, (unsigned)(s + 1), __ATOMIC_RELEASE,
                               __HIP_MEMORY_SCOPE_AGENT);   // wbL2 + store: publish
    }
    #pragma unroll
    for (int mt = 0; mt < 2; ++mt)
        cc[((size_t)d * 64 + bh * 32 + mt * 16 + m16) * 512 + wc * 32 + j] = cst[mt];
}

// ---------------- final linear (reassembles h from HS / S) ----------------
__global__ void k_linear(const unsigned short* __restrict__ hs1,
                         const unsigned short* __restrict__ S,
                         const float* __restrict__ lw, const float* __restrict__ lb,
                         float* __restrict__ feats) {
    int p = blockIdx.x * 4 + (threadIdx.x >> 6);   // row = t*64+b
    int lane = threadIdx.x & 63;
    int t = p >> 6, b = p & 63;
    int col = lane * 16;
    bool hfHalf = col < 512;
    bool useS = hfHalf ? (t < 256) : (t >= 256);
    const unsigned short* rowp = useS
        ? (S + ((size_t)t * 64 + b) * 512 + (col & 511))
        : (hs1 + (size_t)p * 1024 + col);
    uint4 u0 = ((const uint4*)rowp)[0];
    uint4 u1 = ((const uint4*)rowp)[1];
    unsigned int uu[8] = {u0.x, u0.y, u0.z, u0.w, u1.x, u1.y, u1.z, u1.w};
    float x[16];
    #pragma unroll
    for (int i = 0; i < 8; ++i) { x[2*i] = bf2f(uu[i] & 0xffffu); x[2*i+1] = bf2f(uu[i] >> 16); }
    float acc[16];
    #pragma unroll
    for (int c = 0; c < 16; ++c) {
        const float4* w4 = (const float4*)(lw + (size_t)c * 1024 + col);
        float a = 0.f;
        #pragma unroll
        for (int k4 = 0; k4 < 4; ++k4) {
            float4 w = w4[k4];
            a += x[k4*4+0]*w.x + x[k4*4+1]*w.y + x[k4*4+2]*w.z + x[k4*4+3]*w.w;
        }
        acc[c] = a;
    }
    #pragma unroll
    for (int c = 0; c < 16; ++c) {
        #pragma unroll
        for (int off = 32; off; off >>= 1) acc[c] += __shfl_xor(acc[c], off, 64);
    }
    if (lane == 0) {
        float* o = feats + (size_t)b * (kT * kC) + t * kC;
        #pragma unroll
        for (int c = 0; c < 16; ++c) o[c] = acc[c] + lb[c];
    }
}

// ---------------- Viterbi ----------------
__global__ void k_viterbi(const float* __restrict__ feats, const float* __restrict__ trans,
                          float* __restrict__ out) {
    int b = blockIdx.x;
    int lane = threadIdx.x;            // block = 64
    __shared__ unsigned char bp[kT * kC];
    __shared__ float fv[2][kC];
    __shared__ float tbuf[kC];
    float trow[16];
    float tstop = 0.f;
    if (lane < 16) {
        #pragma unroll
        for (int p = 0; p < 16; ++p) trow[p] = trans[lane * 16 + p];
        tstop = trans[kSTOP * 16 + lane];
        fv[0][lane] = (lane == kSTART) ? 0.f : NEGV;
    }
    __syncthreads();
    const float* fb = feats + (size_t)b * (kT * kC);
    for (int t = 0; t < kT; ++t) {
        if (lane < 16) {
            float m = -3.4e38f; int arg = 0;
            #pragma unroll
            for (int p = 0; p < 16; ++p) {
                float v = fv[t & 1][p] + trow[p];
                if (v > m) { m = v; arg = p; }   // strict >: first max = jnp.argmax
            }
            bp[t * 16 + lane] = (unsigned char)arg;
            fv[(t + 1) & 1][lane] = m + fb[t * 16 + lane];
        }
        __syncthreads();
    }
    if (lane < 16) tbuf[lane] = fv[kT & 1][lane] + tstop;
    __syncthreads();
    if (lane == 0) {
        float bm = tbuf[0]; int best = 0;
        #pragma unroll
        for (int p = 1; p < 16; ++p) if (tbuf[p] > bm) { bm = tbuf[p]; best = p; }
        out[b] = bm;
        float* path = out + kB + (size_t)b * kT;
        int tag = best;
        for (int t = kT - 1; t >= 0; --t) {
            path[t] = (float)tag;
            tag = bp[t * 16 + tag];
        }
    }
}

// ---------------- host ----------------
extern "C" void kernel_launch(void* const* d_in, const int* in_sizes, int n_in,
                              void* d_out, int out_size, void* d_ws, size_t ws_size,
                              hipStream_t stream) {
    const int*   sent = (const int*)d_in[0];
    const float* emb  = (const float*)d_in[1];
    const float* wih0 = (const float*)d_in[2];
    const float* whh0 = (const float*)d_in[3];
    const float* bih0 = (const float*)d_in[4];
    const float* bhh0 = (const float*)d_in[5];
    const float* wih1 = (const float*)d_in[6];
    const float* whh1 = (const float*)d_in[7];
    const float* bih1 = (const float*)d_in[8];
    const float* bhh1 = (const float*)d_in[9];
    const float* lw   = (const float*)d_in[10];
    const float* lb   = (const float*)d_in[11];
    const float* tr   = (const float*)d_in[12];
    const float* h0   = (const float*)d_in[13];
    const float* c0   = (const float*)d_in[14];
    float* out = (float*)d_out;

    char* ws = (char*)d_ws;
    size_t off = 0;
    auto alloc = [&](size_t bytes) -> void* {
        void* p = ws + off; off += (bytes + 255) & ~(size_t)255; return p;
    };
    // X0 (32MB) + Wx0 (4MB) dead during layer-1 recurrence; S aliases X0.
    unsigned short* X0    = (unsigned short*)alloc((size_t)kT * kB * 512 * 2);       // 32MB
    unsigned short* Wx0   = (unsigned short*)alloc((size_t)4096 * 512 * 2);          // 4MB
    unsigned short* S     = (unsigned short*)X0;                                     // alias
    unsigned short* Wh0   = (unsigned short*)alloc((size_t)4096 * 512 * 2);          // 4MB
    unsigned short* Wx1   = (unsigned short*)alloc((size_t)4096 * 1024 * 2);         // 8MB
    unsigned short* Wh1   = (unsigned short*)alloc((size_t)4096 * 512 * 2);          // 4MB
    float*          biascat0 = (float*)alloc(4096 * 4);
    float*          biascat1 = (float*)alloc(4096 * 4);
    unsigned short* HS    = (unsigned short*)alloc((size_t)kT * kB * 1024 * 2);      // 67MB
    unsigned short* hcur  = (unsigned short*)alloc((size_t)2 * 2 * 2 * kB * kHD * 2);
    float*          ccur  = (float*)alloc((size_t)4 * kB * kHD * 4);
    float*          feats = (float*)alloc((size_t)kB * kT * kC * 4);
    unsigned int*   flags = (unsigned int*)alloc(256 * 4);
    unsigned short* Gx    = (unsigned short*)alloc((size_t)4096 * 4096 * 2);         // 33.5MB

    // all weights gate-interleave-permuted (row = d*2048 + col*4 + gate)
    k_castWx<<<4096, 128, 0, stream>>>(wih0, Wx0, 512);
    k_castWx<<<4096, 128, 0, stream>>>(whh0, Wh0, 512);
    k_castWx<<<4096, 128, 0, stream>>>(wih1, Wx1, 1024);
    k_castWx<<<4096, 128, 0, stream>>>(whh1, Wh1, 512);
    k_init<<<(4 * kB * kHD + 8192 + 256 + 255) / 256, 256, 0, stream>>>(
        h0, c0, bih0, bhh0, bih1, bhh1, hcur, ccur, biascat0, biascat1, flags);
    k_embed<<<kT * kB, 128, 0, stream>>>(sent, emb, X0);

    unsigned short* hcur1 = hcur + (size_t)131072;
    float*          ccur1 = ccur + (size_t)65536;

    // layer 0: chunked Gx GEMM (K=512) + recurrence -> HS
    for (int ch = 0; ch < kT / kL; ++ch) {
        int s0 = ch * kL;
        k_gemm<<<32 * 32, 256, 0, stream>>>(X0, Wx0, biascat0, Gx, 512,
                                            s0 * 64, (kT - kL - s0) * 64);
        k_rec <<<64, 512, 0, stream>>>(Wh0, Gx, hcur, ccur, HS, S, flags, s0, 0);
    }
    // layer 1: chunked Gx GEMM (K=1024) + recurrence -> HS/S (split routing)
    for (int ch = 0; ch < kT / kL; ++ch) {
        int s0 = ch * kL;
        k_gemm<<<32 * 32, 256, 0, stream>>>(HS, Wx1, biascat1, Gx, 1024,
                                            s0 * 64, (kT - kL - s0) * 64);
        k_rec <<<64, 512, 0, stream>>>(Wh1, Gx, hcur1, ccur1, HS, S, flags + 64, s0, 1);
    }

    k_linear<<<kT * kB / 4, 256, 0, stream>>>(HS, S, lw, lb, feats);
    k_viterbi<<<kB, 64, 0, stream>>>(feats, tr, out);
}

// Round 6
// 10259.989 us; speedup vs baseline: 5.0327x; 1.0451x over previous
//
#include <hip/hip_runtime.h>
#include <stdint.h>

// ---------------- constants ----------------
constexpr int kB  = 64;    // batch
constexpr int kT  = 512;   // seq len
constexpr int kHD = 512;   // per-direction hidden
constexpr int kC  = 16;    // classes
constexpr int kL  = 32;    // time-chunk length
constexpr int kSTART = 14;
constexpr int kSTOP  = 15;
#define NEGV (-10000.0f)

typedef __bf16 bf16x8 __attribute__((ext_vector_type(8)));
typedef float  f32x4  __attribute__((ext_vector_type(4)));

union U16x8 { uint4 u; bf16x8 v; };

__device__ __forceinline__ unsigned short f2bf(float f) {
    union { float f; unsigned int u; } x; x.f = f;
    unsigned int u = x.u;
    u += 0x7fffu + ((u >> 16) & 1u);           // RNE
    return (unsigned short)(u >> 16);
}
__device__ __forceinline__ float bf2f(unsigned int hbits) {
    union { unsigned int u; float f; } x; x.u = hbits << 16;
    return x.f;
}

typedef __attribute__((address_space(1))) const unsigned int GASU;
typedef __attribute__((address_space(3))) unsigned int LASU;
__device__ __forceinline__ void ld_lds16(const unsigned short* g, unsigned short* l) {
    __builtin_amdgcn_global_load_lds((GASU*)g, (LASU*)l, 16, 0, 0);
}

// ---------------- permuting cast: dst row d*2048 + col*4 + gate = src row d*2048 + gate*512 + col
__global__ void k_castWx(const float* __restrict__ src, unsigned short* __restrict__ dst, int K) {
    int np = blockIdx.x;               // 0..4095 dst row
    int dd = np >> 11, r = np & 2047;
    int g = r & 3, cj = r >> 2;
    const float* s = src + ((size_t)(dd * 2048 + g * 512 + cj)) * K;
    unsigned short* d = dst + (size_t)np * K;
    for (int e = threadIdx.x * 8; e < K; e += 128 * 8) {   // block = 128
        float4 a = *(const float4*)(s + e);
        float4 b = *(const float4*)(s + e + 4);
        ushort4 lo, hi;
        lo.x = f2bf(a.x); lo.y = f2bf(a.y); lo.z = f2bf(a.z); lo.w = f2bf(a.w);
        hi.x = f2bf(b.x); hi.y = f2bf(b.y); hi.z = f2bf(b.z); hi.w = f2bf(b.w);
        *(ushort4*)(d + e) = lo; *(ushort4*)(d + e + 4) = hi;
    }
}

// ---------------- embedding gather ----------------
__global__ void k_embed(const int* __restrict__ sent, const float* __restrict__ emb,
                        unsigned short* __restrict__ X0) {
    int row = blockIdx.x;              // t*64 + b
    int t = row >> 6, b = row & 63;
    int v = sent[b * kT + t];
    const float4* src = (const float4*)(emb + (size_t)v * 512);
    float4 f = src[threadIdx.x];       // block = 128
    ushort4 o;
    o.x = f2bf(f.x); o.y = f2bf(f.y); o.z = f2bf(f.z); o.w = f2bf(f.w);
    ((ushort4*)(X0 + (size_t)row * 512))[threadIdx.x] = o;
}

// ---------------- init: h/c states, permuted fused biases, flags ----------------
__global__ void k_init(const float* __restrict__ h0, const float* __restrict__ c0,
                       const float* __restrict__ bih0, const float* __restrict__ bhh0,
                       const float* __restrict__ bih1, const float* __restrict__ bhh1,
                       unsigned short* __restrict__ hcur, float* __restrict__ ccur,
                       float* __restrict__ biascat0, float* __restrict__ biascat1,
                       unsigned int* __restrict__ flags) {
    int i = blockIdx.x * blockDim.x + threadIdx.x;
    const int NS = 4 * kB * kHD;       // 131072
    if (i < NS) {
        int l = i >> 16;
        int rem = i & 65535;           // d*32768 + b*512 + j
        hcur[(size_t)l * 131072 + rem] = f2bf(h0[i]);   // parity-0 region
        ccur[i] = c0[i];
    } else if (i < NS + 8192) {
        int j2 = i - NS;
        int l = j2 >> 12;
        int n = j2 & 4095;             // src: d*2048 + g*512 + col
        int dd = n >> 11, r = n & 2047;
        int g = r >> 9, cj = r & 511;
        float v = l ? (bih1[n] + bhh1[n]) : (bih0[n] + bhh0[n]);
        int np = dd * 2048 + cj * 4 + g;   // gate-interleaved
        (l ? biascat1 : biascat0)[np] = v;
    } else if (i < NS + 8192 + 2048) {
        flags[i - NS - 8192] = 0u;
    }
}

// ---------------- chunk GEMM (m97-style, staging verified R4) ----------------
__launch_bounds__(256, 2)
__global__ void k_gemm(const unsigned short* __restrict__ A,
                       const unsigned short* __restrict__ Bm,
                       const float* __restrict__ bias,
                       unsigned short* __restrict__ Cm,
                       int K, int afwd, int abwd) {
    const int nb = blockIdx.x & 31;
    const int mb = blockIdx.x >> 5;
    const int m0w = mb << 7;
    const int arow0 = (m0w < 2048) ? (afwd + m0w) : (abwd + (m0w - 2048));
    const int n0 = nb << 7;
    const int tid = threadIdx.x;
    const int lane = tid & 63;
    const int wave = tid >> 6;
    const int wm = wave >> 1, wn = wave & 1;
    const int l16 = lane & 15, quad = lane >> 4;
    __shared__ unsigned short As[128 * 32];
    __shared__ unsigned short Bs[128 * 32];
    const int srw = wave * 32 + (lane >> 2);
    const int sc  = lane & 3;
    unsigned short* AsW0 = As + wave * 1024;
    unsigned short* AsW1 = As + wave * 1024 + 512;
    unsigned short* BsW0 = Bs + wave * 1024;
    unsigned short* BsW1 = Bs + wave * 1024 + 512;

    f32x4 acc[4][4];
    #pragma unroll
    for (int i = 0; i < 4; ++i)
        #pragma unroll
        for (int jj = 0; jj < 4; ++jj) acc[i][jj] = (f32x4){0,0,0,0};

    const int kiters = K >> 5;
    for (int kk = 0; kk < kiters; ++kk) {
        __syncthreads();
        ld_lds16(A  + (size_t)(arow0 + srw)      * K + kk * 32 + sc * 8, AsW0);
        ld_lds16(A  + (size_t)(arow0 + srw + 16) * K + kk * 32 + sc * 8, AsW1);
        ld_lds16(Bm + (size_t)(n0 + srw)         * K + kk * 32 + sc * 8, BsW0);
        ld_lds16(Bm + (size_t)(n0 + srw + 16)    * K + kk * 32 + sc * 8, BsW1);
        __syncthreads();
        U16x8 af[4], bf[4];
        #pragma unroll
        for (int i = 0; i < 4; ++i) {
            af[i].u = *(const uint4*)(As + (wm * 64 + i * 16 + l16) * 32 + quad * 8);
            bf[i].u = *(const uint4*)(Bs + (wn * 64 + i * 16 + l16) * 32 + quad * 8);
        }
        #pragma unroll
        for (int i = 0; i < 4; ++i)
            #pragma unroll
            for (int jj = 0; jj < 4; ++jj)
                acc[i][jj] = __builtin_amdgcn_mfma_f32_16x16x32_bf16(af[i].v, bf[jj].v, acc[i][jj], 0, 0, 0);
    }
    #pragma unroll
    for (int jj = 0; jj < 4; ++jj) {
        int n = n0 + wn * 64 + jj * 16 + l16;
        float bv = bias[n];
        #pragma unroll
        for (int i = 0; i < 4; ++i) {
            int mrow = m0w + wm * 64 + i * 16 + quad * 4;
            #pragma unroll
            for (int rr = 0; rr < 4; ++rr)
                Cm[(size_t)(mrow + rr) * 4096 + n] = f2bf(acc[i][jj][rr] + bv);
        }
    }
}

// ---------------- recurrence chunk v3: parallel flag poll, Gx prefetch ----------------
// 64 WGs x 512 thr (8 waves). blk: d = blk>>5, bh = (blk>>4)&1, wc = blk&15.
// Group (d,bh) = 16 WGs. Flags: one per WG, spread to separate 64B lines (stride 16 dw);
// publish = release store; wait = 16 lanes poll 16 flags in parallel (relaxed) + acq fence.
__launch_bounds__(512, 1)
__global__ void k_rec(const unsigned short* __restrict__ Wh,   // [2][2048][512] bf16 PERMUTED
                      const unsigned short* __restrict__ Gx,    // [4096][4096] bf16 chunk
                      unsigned short* __restrict__ hcur,        // [par][dir][64][512] bf16
                      float* __restrict__ cc,                   // [dir][64][512] f32
                      unsigned short* __restrict__ hs,          // HS [512*64][1024]
                      unsigned short* __restrict__ S,           // side buffer [512*64][512]
                      unsigned int* __restrict__ flags,         // [4 groups][16 flags x 16 dw]
                      int s0, int split) {
    const int blk = blockIdx.x;
    const int d  = blk >> 5;
    const int bh = (blk >> 4) & 1;
    const int wc = blk & 15;
    const int tid = threadIdx.x;
    const int wave = tid >> 6;         // 0..7
    const int lane = tid & 63;
    const int l16 = lane & 15;
    const int quad = lane >> 4;

    __shared__ unsigned short zbuf[32 * 520];      // 32 batch rows x 512 k, +8 pad
    __shared__ float gstash[8][16][17];
    __shared__ unsigned short hstash[32 * 32];

    // Wh fragments: wave covers gate rows [wc*128 + wave*16, +16)
    uint4 wreg[16];
    {
        const unsigned short* wrow =
            Wh + ((size_t)d * 2048 + wc * 128 + wave * 16 + l16) * 512 + quad * 8;
        #pragma unroll
        for (int kk = 0; kk < 16; ++kk) wreg[kk] = *(const uint4*)(wrow + kk * 32);
    }
    // cell ownership: thread -> (m16 = tid>>5, j = tid&31), rounds mt = 0,1
    const int m16 = tid >> 5;
    const int j   = tid & 31;
    float cst[2];
    #pragma unroll
    for (int mt = 0; mt < 2; ++mt)
        cst[mt] = cc[((size_t)d * 64 + bh * 32 + mt * 16 + m16) * 512 + wc * 32 + j];

    unsigned int* flg = flags + (d * 2 + bh) * 256;   // 16 flags x 16-dword stride
    const int sr   = tid >> 4;          // staging row 0..31
    const int scol = (tid & 15) * 32;   // staging col (shorts)

    for (int sl = 0; sl < kL; ++sl) {
        const int s = s0 + sl;
        const int t = d ? (kT - 1 - s) : s;
        // ---- prefetch Gx for both mt rounds (independent of h; overlaps the wait) ----
        ushort4 gx4[2];
        #pragma unroll
        for (int mt = 0; mt < 2; ++mt) {
            int b = bh * 32 + mt * 16 + m16;
            int grow = d ? (2048 + (kL - 1 - sl) * 64 + b) : (sl * 64 + b);
            gx4[mt] = *(const ushort4*)(Gx + (size_t)grow * 4096 + d * 2048 + (wc * 32 + j) * 4);
        }
        // ---- wait: all 16 group peers completed step s-1 (parallel poll, 1 lane/flag) ----
        if (sl > 0) {
            if (wave == 0 && lane < 16) {
                unsigned tgt = (unsigned)s;
                while (__hip_atomic_load(flg + lane * 16, __ATOMIC_RELAXED,
                                         __HIP_MEMORY_SCOPE_AGENT) < tgt)
                    __builtin_amdgcn_s_sleep(1);
            }
            __syncthreads();
            __builtin_amdgcn_fence(__ATOMIC_ACQUIRE, "agent");
        }
        // ---- stage h half (32 x 512) into padded LDS ----
        {
            const unsigned short* hread = hcur + ((size_t)((s & 1) * 2 + d) * 64) * 512;
            const uint4* src = (const uint4*)(hread + (size_t)(bh * 32 + sr) * 512 + scol);
            uint4* dst = (uint4*)(zbuf + sr * 520 + scol);
            dst[0] = src[0]; dst[1] = src[1]; dst[2] = src[2]; dst[3] = src[3];
        }
        __syncthreads();
        f32x4 acc[2];
        acc[0] = (f32x4){0, 0, 0, 0};
        acc[1] = (f32x4){0, 0, 0, 0};
        #pragma unroll
        for (int kk = 0; kk < 16; ++kk) {
            U16x8 b; b.u = wreg[kk];
            #pragma unroll
            for (int mt = 0; mt < 2; ++mt) {
                U16x8 a; a.u = *(const uint4*)(zbuf + (mt * 16 + l16) * 520 + kk * 32 + quad * 8);
                acc[mt] = __builtin_amdgcn_mfma_f32_16x16x32_bf16(a.v, b.v, acc[mt], 0, 0, 0);
            }
        }
        // ---- update rounds (gstash reused per mt) ----
        #pragma unroll
        for (int mt = 0; mt < 2; ++mt) {
            __syncthreads();
            #pragma unroll
            for (int rr = 0; rr < 4; ++rr) gstash[wave][quad * 4 + rr][l16] = acc[mt][rr];
            __syncthreads();
            float gi = gstash[j >> 2][m16][(j & 3) * 4 + 0] + bf2f(gx4[mt].x);
            float gf = gstash[j >> 2][m16][(j & 3) * 4 + 1] + bf2f(gx4[mt].y);
            float gg = gstash[j >> 2][m16][(j & 3) * 4 + 2] + bf2f(gx4[mt].z);
            float go = gstash[j >> 2][m16][(j & 3) * 4 + 3] + bf2f(gx4[mt].w);
            float si = 1.f / (1.f + __expf(-gi));
            float sf = 1.f / (1.f + __expf(-gf));
            float so = 1.f / (1.f + __expf(-go));
            float tg = tanhf(gg);
            float cn = sf * cst[mt] + si * tg;
            cst[mt] = cn;
            float hn = so * tanhf(cn);
            hstash[(mt * 16 + m16) * 32 + j] = f2bf(hn);
        }
        __syncthreads();
        // ---- write out h slice + hs/S ----
        {
            int r = tid >> 4, c2 = (tid & 15) * 2;
            unsigned int v = *(const unsigned int*)(hstash + r * 32 + c2);
            unsigned short* hwrite = hcur + ((size_t)(((s + 1) & 1) * 2 + d) * 64) * 512;
            *(unsigned int*)(hwrite + (size_t)(bh * 32 + r) * 512 + wc * 32 + c2) = v;
            int b = bh * 32 + r;
            bool toS = split && (d ? (t >= 256) : (t < 256));
            if (toS)
                *(unsigned int*)(S + ((size_t)t * 64 + b) * 512 + wc * 32 + c2) = v;
            else
                *(unsigned int*)(hs + ((size_t)t * 64 + b) * 1024 + (size_t)d * 512 + wc * 32 + c2) = v;
        }
        __syncthreads();   // all waves' h stores issued (vmcnt drained per-wave)
        if (sl + 1 < kL && tid == 0)
            __hip_atomic_store(flg + wc * 16, (unsigned)(s + 1), __ATOMIC_RELEASE,
                               __HIP_MEMORY_SCOPE_AGENT);   // publish step s+1 readiness
    }
    #pragma unroll
    for (int mt = 0; mt < 2; ++mt)
        cc[((size_t)d * 64 + bh * 32 + mt * 16 + m16) * 512 + wc * 32 + j] = cst[mt];
}

// ---------------- final linear (reassembles h from HS / S) ----------------
__global__ void k_linear(const unsigned short* __restrict__ hs1,
                         const unsigned short* __restrict__ S,
                         const float* __restrict__ lw, const float* __restrict__ lb,
                         float* __restrict__ feats) {
    int p = blockIdx.x * 4 + (threadIdx.x >> 6);   // row = t*64+b
    int lane = threadIdx.x & 63;
    int t = p >> 6, b = p & 63;
    int col = lane * 16;
    bool hfHalf = col < 512;
    bool useS = hfHalf ? (t < 256) : (t >= 256);
    const unsigned short* rowp = useS
        ? (S + ((size_t)t * 64 + b) * 512 + (col & 511))
        : (hs1 + (size_t)p * 1024 + col);
    uint4 u0 = ((const uint4*)rowp)[0];
    uint4 u1 = ((const uint4*)rowp)[1];
    unsigned int uu[8] = {u0.x, u0.y, u0.z, u0.w, u1.x, u1.y, u1.z, u1.w};
    float x[16];
    #pragma unroll
    for (int i = 0; i < 8; ++i) { x[2*i] = bf2f(uu[i] & 0xffffu); x[2*i+1] = bf2f(uu[i] >> 16); }
    float acc[16];
    #pragma unroll
    for (int c = 0; c < 16; ++c) {
        const float4* w4 = (const float4*)(lw + (size_t)c * 1024 + col);
        float a = 0.f;
        #pragma unroll
        for (int k4 = 0; k4 < 4; ++k4) {
            float4 w = w4[k4];
            a += x[k4*4+0]*w.x + x[k4*4+1]*w.y + x[k4*4+2]*w.z + x[k4*4+3]*w.w;
        }
        acc[c] = a;
    }
    #pragma unroll
    for (int c = 0; c < 16; ++c) {
        #pragma unroll
        for (int off = 32; off; off >>= 1) acc[c] += __shfl_xor(acc[c], off, 64);
    }
    if (lane == 0) {
        float* o = feats + (size_t)b * (kT * kC) + t * kC;
        #pragma unroll
        for (int c = 0; c < 16; ++c) o[c] = acc[c] + lb[c];
    }
}

// ---------------- Viterbi ----------------
__global__ void k_viterbi(const float* __restrict__ feats, const float* __restrict__ trans,
                          float* __restrict__ out) {
    int b = blockIdx.x;
    int lane = threadIdx.x;            // block = 64
    __shared__ unsigned char bp[kT * kC];
    __shared__ float fv[2][kC];
    __shared__ float tbuf[kC];
    float trow[16];
    float tstop = 0.f;
    if (lane < 16) {
        #pragma unroll
        for (int p = 0; p < 16; ++p) trow[p] = trans[lane * 16 + p];
        tstop = trans[kSTOP * 16 + lane];
        fv[0][lane] = (lane == kSTART) ? 0.f : NEGV;
    }
    __syncthreads();
    const float* fb = feats + (size_t)b * (kT * kC);
    for (int t = 0; t < kT; ++t) {
        if (lane < 16) {
            float m = -3.4e38f; int arg = 0;
            #pragma unroll
            for (int p = 0; p < 16; ++p) {
                float v = fv[t & 1][p] + trow[p];
                if (v > m) { m = v; arg = p; }   // strict >: first max = jnp.argmax
            }
            bp[t * 16 + lane] = (unsigned char)arg;
            fv[(t + 1) & 1][lane] = m + fb[t * 16 + lane];
        }
        __syncthreads();
    }
    if (lane < 16) tbuf[lane] = fv[kT & 1][lane] + tstop;
    __syncthreads();
    if (lane == 0) {
        float bm = tbuf[0]; int best = 0;
        #pragma unroll
        for (int p = 1; p < 16; ++p) if (tbuf[p] > bm) { bm = tbuf[p]; best = p; }
        out[b] = bm;
        float* path = out + kB + (size_t)b * kT;
        int tag = best;
        for (int t = kT - 1; t >= 0; --t) {
            path[t] = (float)tag;
            tag = bp[t * 16 + tag];
        }
    }
}

// ---------------- host ----------------
extern "C" void kernel_launch(void* const* d_in, const int* in_sizes, int n_in,
                              void* d_out, int out_size, void* d_ws, size_t ws_size,
                              hipStream_t stream) {
    const int*   sent = (const int*)d_in[0];
    const float* emb  = (const float*)d_in[1];
    const float* wih0 = (const float*)d_in[2];
    const float* whh0 = (const float*)d_in[3];
    const float* bih0 = (const float*)d_in[4];
    const float* bhh0 = (const float*)d_in[5];
    const float* wih1 = (const float*)d_in[6];
    const float* whh1 = (const float*)d_in[7];
    const float* bih1 = (const float*)d_in[8];
    const float* bhh1 = (const float*)d_in[9];
    const float* lw   = (const float*)d_in[10];
    const float* lb   = (const float*)d_in[11];
    const float* tr   = (const float*)d_in[12];
    const float* h0   = (const float*)d_in[13];
    const float* c0   = (const float*)d_in[14];
    float* out = (float*)d_out;

    char* ws = (char*)d_ws;
    size_t off = 0;
    auto alloc = [&](size_t bytes) -> void* {
        void* p = ws + off; off += (bytes + 255) & ~(size_t)255; return p;
    };
    // X0 (32MB) + Wx0 (4MB) dead during layer-1 recurrence; S aliases X0.
    unsigned short* X0    = (unsigned short*)alloc((size_t)kT * kB * 512 * 2);       // 32MB
    unsigned short* Wx0   = (unsigned short*)alloc((size_t)4096 * 512 * 2);          // 4MB
    unsigned short* S     = (unsigned short*)X0;                                     // alias
    unsigned short* Wh0   = (unsigned short*)alloc((size_t)4096 * 512 * 2);          // 4MB
    unsigned short* Wx1   = (unsigned short*)alloc((size_t)4096 * 1024 * 2);         // 8MB
    unsigned short* Wh1   = (unsigned short*)alloc((size_t)4096 * 512 * 2);          // 4MB
    float*          biascat0 = (float*)alloc(4096 * 4);
    float*          biascat1 = (float*)alloc(4096 * 4);
    unsigned short* HS    = (unsigned short*)alloc((size_t)kT * kB * 1024 * 2);      // 67MB
    unsigned short* hcur  = (unsigned short*)alloc((size_t)2 * 2 * 2 * kB * kHD * 2);
    float*          ccur  = (float*)alloc((size_t)4 * kB * kHD * 4);
    float*          feats = (float*)alloc((size_t)kB * kT * kC * 4);
    unsigned int*   flags = (unsigned int*)alloc(2048 * 4);   // 2 layers x 4 groups x 16 x 16dw
    unsigned short* Gx    = (unsigned short*)alloc((size_t)4096 * 4096 * 2);         // 33.5MB

    // all weights gate-interleave-permuted (row = d*2048 + col*4 + gate)
    k_castWx<<<4096, 128, 0, stream>>>(wih0, Wx0, 512);
    k_castWx<<<4096, 128, 0, stream>>>(whh0, Wh0, 512);
    k_castWx<<<4096, 128, 0, stream>>>(wih1, Wx1, 1024);
    k_castWx<<<4096, 128, 0, stream>>>(whh1, Wh1, 512);
    k_init<<<(4 * kB * kHD + 8192 + 2048 + 255) / 256, 256, 0, stream>>>(
        h0, c0, bih0, bhh0, bih1, bhh1, hcur, ccur, biascat0, biascat1, flags);
    k_embed<<<kT * kB, 128, 0, stream>>>(sent, emb, X0);

    unsigned short* hcur1 = hcur + (size_t)131072;
    float*          ccur1 = ccur + (size_t)65536;

    // layer 0: chunked Gx GEMM (K=512) + recurrence -> HS
    for (int ch = 0; ch < kT / kL; ++ch) {
        int s0 = ch * kL;
        k_gemm<<<32 * 32, 256, 0, stream>>>(X0, Wx0, biascat0, Gx, 512,
                                            s0 * 64, (kT - kL - s0) * 64);
        k_rec <<<64, 512, 0, stream>>>(Wh0, Gx, hcur, ccur, HS, S, flags, s0, 0);
    }
    // layer 1: chunked Gx GEMM (K=1024) + recurrence -> HS/S (split routing)
    for (int ch = 0; ch < kT / kL; ++ch) {
        int s0 = ch * kL;
        k_gemm<<<32 * 32, 256, 0, stream>>>(HS, Wx1, biascat1, Gx, 1024,
                                            s0 * 64, (kT - kL - s0) * 64);
        k_rec <<<64, 512, 0, stream>>>(Wh1, Gx, hcur1, ccur1, HS, S, flags + 1024, s0, 1);
    }

    k_linear<<<kT * kB / 4, 256, 0, stream>>>(HS, S, lw, lb, feats);
    k_viterbi<<<kB, 64, 0, stream>>>(feats, tr, out);
}

// Round 7
// 6405.537 us; speedup vs baseline: 8.0610x; 1.6017x over previous
//
#include <hip/hip_runtime.h>
#include <stdint.h>

// ---------------- constants ----------------
constexpr int kB  = 64;    // batch
constexpr int kT  = 512;   // seq len
constexpr int kHD = 512;   // per-direction hidden
constexpr int kC  = 16;    // classes
constexpr int kL  = 32;    // time-chunk length
constexpr int kSTART = 14;
constexpr int kSTOP  = 15;
#define NEGV (-10000.0f)

typedef __bf16 bf16x8 __attribute__((ext_vector_type(8)));
typedef float  f32x4  __attribute__((ext_vector_type(4)));

union U16x8 { uint4 u; bf16x8 v; };

__device__ __forceinline__ unsigned short f2bf(float f) {
    union { float f; unsigned int u; } x; x.f = f;
    unsigned int u = x.u;
    u += 0x7fffu + ((u >> 16) & 1u);           // RNE
    return (unsigned short)(u >> 16);
}
__device__ __forceinline__ float bf2f(unsigned int hbits) {
    union { unsigned int u; float f; } x; x.u = hbits << 16;
    return x.f;
}

typedef __attribute__((address_space(1))) const unsigned int GASU;
typedef __attribute__((address_space(3))) unsigned int LASU;
__device__ __forceinline__ void ld_lds16(const unsigned short* g, unsigned short* l) {
    __builtin_amdgcn_global_load_lds((GASU*)g, (LASU*)l, 16, 0, 0);
}

// ---------------- permuting cast: dst row d*2048 + col*4 + gate = src row d*2048 + gate*512 + col
__global__ void k_castWx(const float* __restrict__ src, unsigned short* __restrict__ dst, int K) {
    int np = blockIdx.x;               // 0..4095 dst row
    int dd = np >> 11, r = np & 2047;
    int g = r & 3, cj = r >> 2;
    const float* s = src + ((size_t)(dd * 2048 + g * 512 + cj)) * K;
    unsigned short* d = dst + (size_t)np * K;
    for (int e = threadIdx.x * 8; e < K; e += 128 * 8) {   // block = 128
        float4 a = *(const float4*)(s + e);
        float4 b = *(const float4*)(s + e + 4);
        ushort4 lo, hi;
        lo.x = f2bf(a.x); lo.y = f2bf(a.y); lo.z = f2bf(a.z); lo.w = f2bf(a.w);
        hi.x = f2bf(b.x); hi.y = f2bf(b.y); hi.z = f2bf(b.z); hi.w = f2bf(b.w);
        *(ushort4*)(d + e) = lo; *(ushort4*)(d + e + 4) = hi;
    }
}

// ---------------- embedding gather ----------------
__global__ void k_embed(const int* __restrict__ sent, const float* __restrict__ emb,
                        unsigned short* __restrict__ X0) {
    int row = blockIdx.x;              // t*64 + b
    int t = row >> 6, b = row & 63;
    int v = sent[b * kT + t];
    const float4* src = (const float4*)(emb + (size_t)v * 512);
    float4 f = src[threadIdx.x];       // block = 128
    ushort4 o;
    o.x = f2bf(f.x); o.y = f2bf(f.y); o.z = f2bf(f.z); o.w = f2bf(f.w);
    ((ushort4*)(X0 + (size_t)row * 512))[threadIdx.x] = o;
}

// ---------------- init: h/c states, permuted fused biases, flags ----------------
__global__ void k_init(const float* __restrict__ h0, const float* __restrict__ c0,
                       const float* __restrict__ bih0, const float* __restrict__ bhh0,
                       const float* __restrict__ bih1, const float* __restrict__ bhh1,
                       unsigned short* __restrict__ hcur, float* __restrict__ ccur,
                       float* __restrict__ biascat0, float* __restrict__ biascat1,
                       unsigned int* __restrict__ flags) {
    int i = blockIdx.x * blockDim.x + threadIdx.x;
    const int NS = 4 * kB * kHD;       // 131072
    if (i < NS) {
        int l = i >> 16;
        int rem = i & 65535;           // d*32768 + b*512 + j
        hcur[(size_t)l * 131072 + rem] = f2bf(h0[i]);   // parity-0 region
        ccur[i] = c0[i];
    } else if (i < NS + 8192) {
        int j2 = i - NS;
        int l = j2 >> 12;
        int n = j2 & 4095;             // src: d*2048 + g*512 + col
        int dd = n >> 11, r = n & 2047;
        int g = r >> 9, cj = r & 511;
        float v = l ? (bih1[n] + bhh1[n]) : (bih0[n] + bhh0[n]);
        int np = dd * 2048 + cj * 4 + g;   // gate-interleaved
        (l ? biascat1 : biascat0)[np] = v;
    } else if (i < NS + 8192 + 2048) {
        flags[i - NS - 8192] = 0u;
    }
}

// ---------------- chunk GEMM (m97-style, staging verified R4) ----------------
__launch_bounds__(256, 2)
__global__ void k_gemm(const unsigned short* __restrict__ A,
                       const unsigned short* __restrict__ Bm,
                       const float* __restrict__ bias,
                       unsigned short* __restrict__ Cm,
                       int K, int afwd, int abwd) {
    const int nb = blockIdx.x & 31;
    const int mb = blockIdx.x >> 5;
    const int m0w = mb << 7;
    const int arow0 = (m0w < 2048) ? (afwd + m0w) : (abwd + (m0w - 2048));
    const int n0 = nb << 7;
    const int tid = threadIdx.x;
    const int lane = tid & 63;
    const int wave = tid >> 6;
    const int wm = wave >> 1, wn = wave & 1;
    const int l16 = lane & 15, quad = lane >> 4;
    __shared__ unsigned short As[128 * 32];
    __shared__ unsigned short Bs[128 * 32];
    const int srw = wave * 32 + (lane >> 2);
    const int sc  = lane & 3;
    unsigned short* AsW0 = As + wave * 1024;
    unsigned short* AsW1 = As + wave * 1024 + 512;
    unsigned short* BsW0 = Bs + wave * 1024;
    unsigned short* BsW1 = Bs + wave * 1024 + 512;

    f32x4 acc[4][4];
    #pragma unroll
    for (int i = 0; i < 4; ++i)
        #pragma unroll
        for (int jj = 0; jj < 4; ++jj) acc[i][jj] = (f32x4){0,0,0,0};

    const int kiters = K >> 5;
    for (int kk = 0; kk < kiters; ++kk) {
        __syncthreads();
        ld_lds16(A  + (size_t)(arow0 + srw)      * K + kk * 32 + sc * 8, AsW0);
        ld_lds16(A  + (size_t)(arow0 + srw + 16) * K + kk * 32 + sc * 8, AsW1);
        ld_lds16(Bm + (size_t)(n0 + srw)         * K + kk * 32 + sc * 8, BsW0);
        ld_lds16(Bm + (size_t)(n0 + srw + 16)    * K + kk * 32 + sc * 8, BsW1);
        __syncthreads();
        U16x8 af[4], bf[4];
        #pragma unroll
        for (int i = 0; i < 4; ++i) {
            af[i].u = *(const uint4*)(As + (wm * 64 + i * 16 + l16) * 32 + quad * 8);
            bf[i].u = *(const uint4*)(Bs + (wn * 64 + i * 16 + l16) * 32 + quad * 8);
        }
        #pragma unroll
        for (int i = 0; i < 4; ++i)
            #pragma unroll
            for (int jj = 0; jj < 4; ++jj)
                acc[i][jj] = __builtin_amdgcn_mfma_f32_16x16x32_bf16(af[i].v, bf[jj].v, acc[i][jj], 0, 0, 0);
    }
    #pragma unroll
    for (int jj = 0; jj < 4; ++jj) {
        int n = n0 + wn * 64 + jj * 16 + l16;
        float bv = bias[n];
        #pragma unroll
        for (int i = 0; i < 4; ++i) {
            int mrow = m0w + wm * 64 + i * 16 + quad * 4;
            #pragma unroll
            for (int rr = 0; rr < 4; ++rr)
                Cm[(size_t)(mrow + rr) * 4096 + n] = f2bf(acc[i][jj][rr] + bv);
        }
    }
}

// ---------------- recurrence chunk v4: fence-free h exchange via agent-scope sc ops -----
// 64 WGs x 512 thr (8 waves). blk: d = blk>>5, bh = (blk>>4)&1, wc = blk&15.
// Group (d,bh) = 16 WGs. h exchanged with RELAXED agent atomics (L2-bypassing, L3-coherent)
// -> no buffer_wbl2 / buffer_inv per step; L2 stays warm for Gx/bias.
// Ordering: producer drains stores via __syncthreads (vmcnt0) before RELAXED flag store;
// consumer's h loads issue only after the poll branch resolves (in-order wave).
__launch_bounds__(512, 1)
__global__ void k_rec(const unsigned short* __restrict__ Wh,   // [2][2048][512] bf16 PERMUTED
                      const unsigned short* __restrict__ Gx,    // [4096][4096] bf16 chunk
                      unsigned short* __restrict__ hcur,        // [par][dir][64][512] bf16
                      float* __restrict__ cc,                   // [dir][64][512] f32
                      unsigned short* __restrict__ hs,          // HS [512*64][1024]
                      unsigned short* __restrict__ S,           // side buffer [512*64][512]
                      unsigned int* __restrict__ flags,         // [4 groups][16 flags x 16 dw]
                      int s0, int split) {
    const int blk = blockIdx.x;
    const int d  = blk >> 5;
    const int bh = (blk >> 4) & 1;
    const int wc = blk & 15;
    const int tid = threadIdx.x;
    const int wave = tid >> 6;         // 0..7
    const int lane = tid & 63;
    const int l16 = lane & 15;
    const int quad = lane >> 4;

    __shared__ unsigned short zbuf[32 * 520];      // 32 batch rows x 512 k, +8 pad
    __shared__ float gstash[2][8][16][17];         // per-mt buffers (fewer syncs)
    __shared__ unsigned short hstash[32 * 32];

    // Wh fragments: wave covers gate rows [wc*128 + wave*16, +16)
    uint4 wreg[16];
    {
        const unsigned short* wrow =
            Wh + ((size_t)d * 2048 + wc * 128 + wave * 16 + l16) * 512 + quad * 8;
        #pragma unroll
        for (int kk = 0; kk < 16; ++kk) wreg[kk] = *(const uint4*)(wrow + kk * 32);
    }
    // cell ownership: thread -> (m16 = tid>>5, j = tid&31), rounds mt = 0,1
    const int m16 = tid >> 5;
    const int j   = tid & 31;
    float cst[2];
    #pragma unroll
    for (int mt = 0; mt < 2; ++mt)
        cst[mt] = cc[((size_t)d * 64 + bh * 32 + mt * 16 + m16) * 512 + wc * 32 + j];

    unsigned int* flg = flags + (d * 2 + bh) * 256;   // 16 flags x 16-dword stride

    for (int sl = 0; sl < kL; ++sl) {
        const int s = s0 + sl;
        const int t = d ? (kT - 1 - s) : s;
        // ---- prefetch Gx for both mt rounds (plain loads; L2 stays warm now) ----
        ushort4 gx4[2];
        #pragma unroll
        for (int mt = 0; mt < 2; ++mt) {
            int b = bh * 32 + mt * 16 + m16;
            int grow = d ? (2048 + (kL - 1 - sl) * 64 + b) : (sl * 64 + b);
            gx4[mt] = *(const ushort4*)(Gx + (size_t)grow * 4096 + d * 2048 + (wc * 32 + j) * 4);
        }
        // ---- wait: all 16 group peers completed step s-1 (parallel poll, no fence) ----
        if (sl > 0) {
            if (wave == 0 && lane < 16) {
                unsigned tgt = (unsigned)s;
                while (__hip_atomic_load(flg + lane * 16, __ATOMIC_RELAXED,
                                         __HIP_MEMORY_SCOPE_AGENT) < tgt)
                    __builtin_amdgcn_s_sleep(1);
            }
            __syncthreads();
        }
        // ---- stage h half (32 x 512 shorts = 4096 ulongs) via L2-bypassing atomic loads ----
        {
            const unsigned long long* hread = (const unsigned long long*)
                (hcur + ((size_t)((s & 1) * 2 + d) * 64 + bh * 32) * 512);
            #pragma unroll
            for (int k = 0; k < 8; ++k) {
                int idx = tid + k * 512;           // ulong index; 128 ulongs per row
                int r = idx >> 7, c8 = idx & 127;
                unsigned long long v = __hip_atomic_load(hread + r * 128 + c8,
                                                         __ATOMIC_RELAXED,
                                                         __HIP_MEMORY_SCOPE_AGENT);
                *(unsigned long long*)(zbuf + r * 520 + c8 * 4) = v;
            }
        }
        __syncthreads();                            // S1: zbuf ready
        f32x4 acc[2];
        acc[0] = (f32x4){0, 0, 0, 0};
        acc[1] = (f32x4){0, 0, 0, 0};
        #pragma unroll
        for (int kk = 0; kk < 16; ++kk) {
            U16x8 b; b.u = wreg[kk];
            #pragma unroll
            for (int mt = 0; mt < 2; ++mt) {
                U16x8 a; a.u = *(const uint4*)(zbuf + (mt * 16 + l16) * 520 + kk * 32 + quad * 8);
                acc[mt] = __builtin_amdgcn_mfma_f32_16x16x32_bf16(a.v, b.v, acc[mt], 0, 0, 0);
            }
        }
        #pragma unroll
        for (int mt = 0; mt < 2; ++mt)
            #pragma unroll
            for (int rr = 0; rr < 4; ++rr)
                gstash[mt][wave][quad * 4 + rr][l16] = acc[mt][rr];
        __syncthreads();                            // S2: gstash ready, zbuf free
        // ---- cell update (c in registers), both rounds ----
        #pragma unroll
        for (int mt = 0; mt < 2; ++mt) {
            float gi = gstash[mt][j >> 2][m16][(j & 3) * 4 + 0] + bf2f(gx4[mt].x);
            float gf = gstash[mt][j >> 2][m16][(j & 3) * 4 + 1] + bf2f(gx4[mt].y);
            float gg = gstash[mt][j >> 2][m16][(j & 3) * 4 + 2] + bf2f(gx4[mt].z);
            float go = gstash[mt][j >> 2][m16][(j & 3) * 4 + 3] + bf2f(gx4[mt].w);
            float si = 1.f / (1.f + __expf(-gi));
            float sf = 1.f / (1.f + __expf(-gf));
            float so = 1.f / (1.f + __expf(-go));
            float tg = tanhf(gg);
            float cn = sf * cst[mt] + si * tg;
            cst[mt] = cn;
            float hn = so * tanhf(cn);
            hstash[(mt * 16 + m16) * 32 + j] = f2bf(hn);
        }
        __syncthreads();                            // S3: hstash ready
        // ---- write out: hcur via agent atomics (write-through), hs/S plain ----
        if (tid < 256) {
            int r = tid >> 3, u = tid & 7;          // 32 rows x 8 ulongs (64B) per row
            unsigned long long val = *(const unsigned long long*)(hstash + r * 32 + u * 4);
            unsigned long long* hwrite = (unsigned long long*)
                (hcur + ((size_t)(((s + 1) & 1) * 2 + d) * 64 + bh * 32) * 512);
            __hip_atomic_store(hwrite + r * 128 + wc * 8 + u, val,
                               __ATOMIC_RELAXED, __HIP_MEMORY_SCOPE_AGENT);
            int b = bh * 32 + r;
            bool toS = split && (d ? (t >= 256) : (t < 256));
            if (toS)
                *(unsigned long long*)(S + ((size_t)t * 64 + b) * 512 + wc * 32 + u * 4) = val;
            else
                *(unsigned long long*)(hs + ((size_t)t * 64 + b) * 1024 + (size_t)d * 512 + wc * 32 + u * 4) = val;
        }
        __syncthreads();                            // S4: all stores drained (vmcnt 0)
        if (sl + 1 < kL && tid == 0)
            __hip_atomic_store(flg + wc * 16, (unsigned)(s + 1),
                               __ATOMIC_RELAXED, __HIP_MEMORY_SCOPE_AGENT);
    }
    #pragma unroll
    for (int mt = 0; mt < 2; ++mt)
        cc[((size_t)d * 64 + bh * 32 + mt * 16 + m16) * 512 + wc * 32 + j] = cst[mt];
}

// ---------------- final linear (reassembles h from HS / S) ----------------
__global__ void k_linear(const unsigned short* __restrict__ hs1,
                         const unsigned short* __restrict__ S,
                         const float* __restrict__ lw, const float* __restrict__ lb,
                         float* __restrict__ feats) {
    int p = blockIdx.x * 4 + (threadIdx.x >> 6);   // row = t*64+b
    int lane = threadIdx.x & 63;
    int t = p >> 6, b = p & 63;
    int col = lane * 16;
    bool hfHalf = col < 512;
    bool useS = hfHalf ? (t < 256) : (t >= 256);
    const unsigned short* rowp = useS
        ? (S + ((size_t)t * 64 + b) * 512 + (col & 511))
        : (hs1 + (size_t)p * 1024 + col);
    uint4 u0 = ((const uint4*)rowp)[0];
    uint4 u1 = ((const uint4*)rowp)[1];
    unsigned int uu[8] = {u0.x, u0.y, u0.z, u0.w, u1.x, u1.y, u1.z, u1.w};
    float x[16];
    #pragma unroll
    for (int i = 0; i < 8; ++i) { x[2*i] = bf2f(uu[i] & 0xffffu); x[2*i+1] = bf2f(uu[i] >> 16); }
    float acc[16];
    #pragma unroll
    for (int c = 0; c < 16; ++c) {
        const float4* w4 = (const float4*)(lw + (size_t)c * 1024 + col);
        float a = 0.f;
        #pragma unroll
        for (int k4 = 0; k4 < 4; ++k4) {
            float4 w = w4[k4];
            a += x[k4*4+0]*w.x + x[k4*4+1]*w.y + x[k4*4+2]*w.z + x[k4*4+3]*w.w;
        }
        acc[c] = a;
    }
    #pragma unroll
    for (int c = 0; c < 16; ++c) {
        #pragma unroll
        for (int off = 32; off; off >>= 1) acc[c] += __shfl_xor(acc[c], off, 64);
    }
    if (lane == 0) {
        float* o = feats + (size_t)b * (kT * kC) + t * kC;
        #pragma unroll
        for (int c = 0; c < 16; ++c) o[c] = acc[c] + lb[c];
    }
}

// ---------------- Viterbi ----------------
__global__ void k_viterbi(const float* __restrict__ feats, const float* __restrict__ trans,
                          float* __restrict__ out) {
    int b = blockIdx.x;
    int lane = threadIdx.x;            // block = 64
    __shared__ unsigned char bp[kT * kC];
    __shared__ float fv[2][kC];
    __shared__ float tbuf[kC];
    float trow[16];
    float tstop = 0.f;
    if (lane < 16) {
        #pragma unroll
        for (int p = 0; p < 16; ++p) trow[p] = trans[lane * 16 + p];
        tstop = trans[kSTOP * 16 + lane];
        fv[0][lane] = (lane == kSTART) ? 0.f : NEGV;
    }
    __syncthreads();
    const float* fb = feats + (size_t)b * (kT * kC);
    for (int t = 0; t < kT; ++t) {
        if (lane < 16) {
            float m = -3.4e38f; int arg = 0;
            #pragma unroll
            for (int p = 0; p < 16; ++p) {
                float v = fv[t & 1][p] + trow[p];
                if (v > m) { m = v; arg = p; }   // strict >: first max = jnp.argmax
            }
            bp[t * 16 + lane] = (unsigned char)arg;
            fv[(t + 1) & 1][lane] = m + fb[t * 16 + lane];
        }
        __syncthreads();
    }
    if (lane < 16) tbuf[lane] = fv[kT & 1][lane] + tstop;
    __syncthreads();
    if (lane == 0) {
        float bm = tbuf[0]; int best = 0;
        #pragma unroll
        for (int p = 1; p < 16; ++p) if (tbuf[p] > bm) { bm = tbuf[p]; best = p; }
        out[b] = bm;
        float* path = out + kB + (size_t)b * kT;
        int tag = best;
        for (int t = kT - 1; t >= 0; --t) {
            path[t] = (float)tag;
            tag = bp[t * 16 + tag];
        }
    }
}

// ---------------- host ----------------
extern "C" void kernel_launch(void* const* d_in, const int* in_sizes, int n_in,
                              void* d_out, int out_size, void* d_ws, size_t ws_size,
                              hipStream_t stream) {
    const int*   sent = (const int*)d_in[0];
    const float* emb  = (const float*)d_in[1];
    const float* wih0 = (const float*)d_in[2];
    const float* whh0 = (const float*)d_in[3];
    const float* bih0 = (const float*)d_in[4];
    const float* bhh0 = (const float*)d_in[5];
    const float* wih1 = (const float*)d_in[6];
    const float* whh1 = (const float*)d_in[7];
    const float* bih1 = (const float*)d_in[8];
    const float* bhh1 = (const float*)d_in[9];
    const float* lw   = (const float*)d_in[10];
    const float* lb   = (const float*)d_in[11];
    const float* tr   = (const float*)d_in[12];
    const float* h0   = (const float*)d_in[13];
    const float* c0   = (const float*)d_in[14];
    float* out = (float*)d_out;

    char* ws = (char*)d_ws;
    size_t off = 0;
    auto alloc = [&](size_t bytes) -> void* {
        void* p = ws + off; off += (bytes + 255) & ~(size_t)255; return p;
    };
    // X0 (32MB) + Wx0 (4MB) dead during layer-1 recurrence; S aliases X0.
    unsigned short* X0    = (unsigned short*)alloc((size_t)kT * kB * 512 * 2);       // 32MB
    unsigned short* Wx0   = (unsigned short*)alloc((size_t)4096 * 512 * 2);          // 4MB
    unsigned short* S     = (unsigned short*)X0;                                     // alias
    unsigned short* Wh0   = (unsigned short*)alloc((size_t)4096 * 512 * 2);          // 4MB
    unsigned short* Wx1   = (unsigned short*)alloc((size_t)4096 * 1024 * 2);         // 8MB
    unsigned short* Wh1   = (unsigned short*)alloc((size_t)4096 * 512 * 2);          // 4MB
    float*          biascat0 = (float*)alloc(4096 * 4);
    float*          biascat1 = (float*)alloc(4096 * 4);
    unsigned short* HS    = (unsigned short*)alloc((size_t)kT * kB * 1024 * 2);      // 67MB
    unsigned short* hcur  = (unsigned short*)alloc((size_t)2 * 2 * 2 * kB * kHD * 2);
    float*          ccur  = (float*)alloc((size_t)4 * kB * kHD * 4);
    float*          feats = (float*)alloc((size_t)kB * kT * kC * 4);
    unsigned int*   flags = (unsigned int*)alloc(2048 * 4);   // 2 layers x 4 groups x 16 x 16dw
    unsigned short* Gx    = (unsigned short*)alloc((size_t)4096 * 4096 * 2);         // 33.5MB

    // all weights gate-interleave-permuted (row = d*2048 + col*4 + gate)
    k_castWx<<<4096, 128, 0, stream>>>(wih0, Wx0, 512);
    k_castWx<<<4096, 128, 0, stream>>>(whh0, Wh0, 512);
    k_castWx<<<4096, 128, 0, stream>>>(wih1, Wx1, 1024);
    k_castWx<<<4096, 128, 0, stream>>>(whh1, Wh1, 512);
    k_init<<<(4 * kB * kHD + 8192 + 2048 + 255) / 256, 256, 0, stream>>>(
        h0, c0, bih0, bhh0, bih1, bhh1, hcur, ccur, biascat0, biascat1, flags);
    k_embed<<<kT * kB, 128, 0, stream>>>(sent, emb, X0);

    unsigned short* hcur1 = hcur + (size_t)131072;
    float*          ccur1 = ccur + (size_t)65536;

    // layer 0: chunked Gx GEMM (K=512) + recurrence -> HS
    for (int ch = 0; ch < kT / kL; ++ch) {
        int s0 = ch * kL;
        k_gemm<<<32 * 32, 256, 0, stream>>>(X0, Wx0, biascat0, Gx, 512,
                                            s0 * 64, (kT - kL - s0) * 64);
        k_rec <<<64, 512, 0, stream>>>(Wh0, Gx, hcur, ccur, HS, S, flags, s0, 0);
    }
    // layer 1: chunked Gx GEMM (K=1024) + recurrence -> HS/S (split routing)
    for (int ch = 0; ch < kT / kL; ++ch) {
        int s0 = ch * kL;
        k_gemm<<<32 * 32, 256, 0, stream>>>(HS, Wx1, biascat1, Gx, 1024,
                                            s0 * 64, (kT - kL - s0) * 64);
        k_rec <<<64, 512, 0, stream>>>(Wh1, Gx, hcur1, ccur1, HS, S, flags + 1024, s0, 1);
    }

    k_linear<<<kT * kB / 4, 256, 0, stream>>>(HS, S, lw, lb, feats);
    k_viterbi<<<kB, 64, 0, stream>>>(feats, tr, out);
}

// Round 8
// 5456.831 us; speedup vs baseline: 9.4625x; 1.1739x over previous
//
#include <hip/hip_runtime.h>
#include <stdint.h>

// ---------------- constants ----------------
constexpr int kB  = 64;    // batch
constexpr int kT  = 512;   // seq len
constexpr int kHD = 512;   // per-direction hidden
constexpr int kC  = 16;    // classes
constexpr int kL  = 32;    // time-chunk length
constexpr int kSTART = 14;
constexpr int kSTOP  = 15;
#define NEGV (-10000.0f)

typedef __bf16 bf16x8 __attribute__((ext_vector_type(8)));
typedef float  f32x4  __attribute__((ext_vector_type(4)));

union U16x8 { uint4 u; bf16x8 v; };

__device__ __forceinline__ unsigned short f2bf(float f) {
    union { float f; unsigned int u; } x; x.f = f;
    unsigned int u = x.u;
    u += 0x7fffu + ((u >> 16) & 1u);           // RNE
    return (unsigned short)(u >> 16);
}
__device__ __forceinline__ float bf2f(unsigned int hbits) {
    union { unsigned int u; float f; } x; x.u = hbits << 16;
    return x.f;
}

typedef __attribute__((address_space(1))) const unsigned int GASU;
typedef __attribute__((address_space(3))) unsigned int LASU;
__device__ __forceinline__ void ld_lds16(const unsigned short* g, unsigned short* l) {
    __builtin_amdgcn_global_load_lds((GASU*)g, (LASU*)l, 16, 0, 0);
}

// ---------------- permuting cast: dst row d*2048 + col*4 + gate = src row d*2048 + gate*512 + col
__global__ void k_castWx(const float* __restrict__ src, unsigned short* __restrict__ dst, int K) {
    int np = blockIdx.x;               // 0..4095 dst row
    int dd = np >> 11, r = np & 2047;
    int g = r & 3, cj = r >> 2;
    const float* s = src + ((size_t)(dd * 2048 + g * 512 + cj)) * K;
    unsigned short* d = dst + (size_t)np * K;
    for (int e = threadIdx.x * 8; e < K; e += 128 * 8) {   // block = 128
        float4 a = *(const float4*)(s + e);
        float4 b = *(const float4*)(s + e + 4);
        ushort4 lo, hi;
        lo.x = f2bf(a.x); lo.y = f2bf(a.y); lo.z = f2bf(a.z); lo.w = f2bf(a.w);
        hi.x = f2bf(b.x); hi.y = f2bf(b.y); hi.z = f2bf(b.z); hi.w = f2bf(b.w);
        *(ushort4*)(d + e) = lo; *(ushort4*)(d + e + 4) = hi;
    }
}

// ---------------- embedding gather ----------------
__global__ void k_embed(const int* __restrict__ sent, const float* __restrict__ emb,
                        unsigned short* __restrict__ X0) {
    int row = blockIdx.x;              // t*64 + b
    int t = row >> 6, b = row & 63;
    int v = sent[b * kT + t];
    const float4* src = (const float4*)(emb + (size_t)v * 512);
    float4 f = src[threadIdx.x];       // block = 128
    ushort4 o;
    o.x = f2bf(f.x); o.y = f2bf(f.y); o.z = f2bf(f.z); o.w = f2bf(f.w);
    ((ushort4*)(X0 + (size_t)row * 512))[threadIdx.x] = o;
}

// ---------------- init: h/c states, permuted fused biases, flags, lw->bf16 ----------------
__global__ void k_init(const float* __restrict__ h0, const float* __restrict__ c0,
                       const float* __restrict__ bih0, const float* __restrict__ bhh0,
                       const float* __restrict__ bih1, const float* __restrict__ bhh1,
                       const float* __restrict__ lw,
                       unsigned short* __restrict__ hcur, float* __restrict__ ccur,
                       float* __restrict__ biascat0, float* __restrict__ biascat1,
                       unsigned int* __restrict__ flags, unsigned short* __restrict__ lwb) {
    int i = blockIdx.x * blockDim.x + threadIdx.x;
    const int NS = 4 * kB * kHD;       // 131072
    if (i < NS) {
        int l = i >> 16;
        int rem = i & 65535;           // d*32768 + b*512 + j
        hcur[(size_t)l * 131072 + rem] = f2bf(h0[i]);   // parity-0 region
        ccur[i] = c0[i];
    } else if (i < NS + 8192) {
        int j2 = i - NS;
        int l = j2 >> 12;
        int n = j2 & 4095;             // src: d*2048 + g*512 + col
        int dd = n >> 11, r = n & 2047;
        int g = r >> 9, cj = r & 511;
        float v = l ? (bih1[n] + bhh1[n]) : (bih0[n] + bhh0[n]);
        int np = dd * 2048 + cj * 4 + g;   // gate-interleaved
        (l ? biascat1 : biascat0)[np] = v;
    } else if (i < NS + 8192 + 2048) {
        flags[i - NS - 8192] = 0u;
    } else if (i < NS + 8192 + 2048 + 16384) {
        int idx = i - NS - 8192 - 2048;
        lwb[idx] = f2bf(lw[idx]);
    }
}

// ---------------- standalone chunk GEMM (lead-in only) ----------------
__launch_bounds__(256, 2)
__global__ void k_gemm(const unsigned short* __restrict__ A,
                       const unsigned short* __restrict__ Bm,
                       const float* __restrict__ bias,
                       unsigned short* __restrict__ Cm,
                       int K, int afwd, int abwd) {
    const int nb = blockIdx.x & 31;
    const int mb = blockIdx.x >> 5;
    const int m0w = mb << 7;
    const int arow0 = (m0w < 2048) ? (afwd + m0w) : (abwd + (m0w - 2048));
    const int n0 = nb << 7;
    const int tid = threadIdx.x;
    const int lane = tid & 63;
    const int wave = tid >> 6;
    const int wm = wave >> 1, wn = wave & 1;
    const int l16 = lane & 15, quad = lane >> 4;
    __shared__ unsigned short As[128 * 32];
    __shared__ unsigned short Bs[128 * 32];
    const int srw = wave * 32 + (lane >> 2);
    const int sc  = lane & 3;
    unsigned short* AsW0 = As + wave * 1024;
    unsigned short* AsW1 = As + wave * 1024 + 512;
    unsigned short* BsW0 = Bs + wave * 1024;
    unsigned short* BsW1 = Bs + wave * 1024 + 512;

    f32x4 acc[4][4];
    #pragma unroll
    for (int i = 0; i < 4; ++i)
        #pragma unroll
        for (int jj = 0; jj < 4; ++jj) acc[i][jj] = (f32x4){0,0,0,0};

    const int kiters = K >> 5;
    for (int kk = 0; kk < kiters; ++kk) {
        __syncthreads();
        ld_lds16(A  + (size_t)(arow0 + srw)      * K + kk * 32 + sc * 8, AsW0);
        ld_lds16(A  + (size_t)(arow0 + srw + 16) * K + kk * 32 + sc * 8, AsW1);
        ld_lds16(Bm + (size_t)(n0 + srw)         * K + kk * 32 + sc * 8, BsW0);
        ld_lds16(Bm + (size_t)(n0 + srw + 16)    * K + kk * 32 + sc * 8, BsW1);
        __syncthreads();
        U16x8 af[4], bf[4];
        #pragma unroll
        for (int i = 0; i < 4; ++i) {
            af[i].u = *(const uint4*)(As + (wm * 64 + i * 16 + l16) * 32 + quad * 8);
            bf[i].u = *(const uint4*)(Bs + (wn * 64 + i * 16 + l16) * 32 + quad * 8);
        }
        #pragma unroll
        for (int i = 0; i < 4; ++i)
            #pragma unroll
            for (int jj = 0; jj < 4; ++jj)
                acc[i][jj] = __builtin_amdgcn_mfma_f32_16x16x32_bf16(af[i].v, bf[jj].v, acc[i][jj], 0, 0, 0);
    }
    #pragma unroll
    for (int jj = 0; jj < 4; ++jj) {
        int n = n0 + wn * 64 + jj * 16 + l16;
        float bv = bias[n];
        #pragma unroll
        for (int i = 0; i < 4; ++i) {
            int mrow = m0w + wm * 64 + i * 16 + quad * 4;
            #pragma unroll
            for (int rr = 0; rr < 4; ++rr)
                Cm[(size_t)(mrow + rr) * 4096 + n] = f2bf(acc[i][jj][rr] + bv);
        }
    }
}

// ---------------- fused: rec chunk (blocks 0..63) + next-chunk GEMM (blocks 64..255) ----
// rec: identical to R7 v4 (fence-free agent-atomic h exchange).
// gemm: 192 WGs x 512 thr; each WG = two 128x128 tiles (half = tid>>8), grid-stride over
// the 512 tile-pairs. GEMM WGs never wait on rec WGs -> no deadlock under any dispatch order.
__launch_bounds__(512, 1)
__global__ void k_fused(const unsigned short* __restrict__ Wh,   // [2][2048][512] bf16 PERMUTED
                        const unsigned short* __restrict__ Gx,    // rec input chunk
                        unsigned short* __restrict__ hcur,
                        float* __restrict__ cc,
                        unsigned short* __restrict__ hs,          // HS
                        unsigned short* __restrict__ S,
                        unsigned int* __restrict__ flags,
                        int s0, int split,
                        const unsigned short* __restrict__ Ag,    // gemm A
                        const unsigned short* __restrict__ Wxg,   // gemm B
                        const float* __restrict__ biasg,
                        unsigned short* __restrict__ Gxout,       // gemm out (other buffer)
                        int Kg, int gfwd, int gbwd, int do_gemm) {
    __shared__ __align__(16) char smem[52736];
    const int tid = threadIdx.x;

    if (blockIdx.x < 64) {
        // ================= recurrence =================
        unsigned short* zbuf   = (unsigned short*)smem;             // 32*520*2 = 33280 B
        float*          gs     = (float*)(smem + 33280);            // 2*8*16*17*4 = 17408 B
        unsigned short* hstash = (unsigned short*)(smem + 50688);   // 2048 B
        const int blk = blockIdx.x;
        const int d  = blk >> 5;
        const int bh = (blk >> 4) & 1;
        const int wc = blk & 15;
        const int wave = tid >> 6;
        const int lane = tid & 63;
        const int l16 = lane & 15;
        const int quad = lane >> 4;

        uint4 wreg[16];
        {
            const unsigned short* wrow =
                Wh + ((size_t)d * 2048 + wc * 128 + wave * 16 + l16) * 512 + quad * 8;
            #pragma unroll
            for (int kk = 0; kk < 16; ++kk) wreg[kk] = *(const uint4*)(wrow + kk * 32);
        }
        const int m16 = tid >> 5;
        const int j   = tid & 31;
        float cst[2];
        #pragma unroll
        for (int mt = 0; mt < 2; ++mt)
            cst[mt] = cc[((size_t)d * 64 + bh * 32 + mt * 16 + m16) * 512 + wc * 32 + j];

        unsigned int* flg = flags + (d * 2 + bh) * 256;

        for (int sl = 0; sl < kL; ++sl) {
            const int s = s0 + sl;
            const int t = d ? (kT - 1 - s) : s;
            ushort4 gx4[2];
            #pragma unroll
            for (int mt = 0; mt < 2; ++mt) {
                int b = bh * 32 + mt * 16 + m16;
                int grow = d ? (2048 + (kL - 1 - sl) * 64 + b) : (sl * 64 + b);
                gx4[mt] = *(const ushort4*)(Gx + (size_t)grow * 4096 + d * 2048 + (wc * 32 + j) * 4);
            }
            if (sl > 0) {
                if (wave == 0 && lane < 16) {
                    unsigned tgt = (unsigned)s;
                    while (__hip_atomic_load(flg + lane * 16, __ATOMIC_RELAXED,
                                             __HIP_MEMORY_SCOPE_AGENT) < tgt)
                        __builtin_amdgcn_s_sleep(1);
                }
                __syncthreads();
            }
            {
                const unsigned long long* hread = (const unsigned long long*)
                    (hcur + ((size_t)((s & 1) * 2 + d) * 64 + bh * 32) * 512);
                #pragma unroll
                for (int k = 0; k < 8; ++k) {
                    int idx = tid + k * 512;
                    int r = idx >> 7, c8 = idx & 127;
                    unsigned long long v = __hip_atomic_load(hread + r * 128 + c8,
                                                             __ATOMIC_RELAXED,
                                                             __HIP_MEMORY_SCOPE_AGENT);
                    *(unsigned long long*)(zbuf + r * 520 + c8 * 4) = v;
                }
            }
            __syncthreads();
            f32x4 acc[2];
            acc[0] = (f32x4){0, 0, 0, 0};
            acc[1] = (f32x4){0, 0, 0, 0};
            #pragma unroll
            for (int kk = 0; kk < 16; ++kk) {
                U16x8 b; b.u = wreg[kk];
                #pragma unroll
                for (int mt = 0; mt < 2; ++mt) {
                    U16x8 a; a.u = *(const uint4*)(zbuf + (mt * 16 + l16) * 520 + kk * 32 + quad * 8);
                    acc[mt] = __builtin_amdgcn_mfma_f32_16x16x32_bf16(a.v, b.v, acc[mt], 0, 0, 0);
                }
            }
            #pragma unroll
            for (int mt = 0; mt < 2; ++mt)
                #pragma unroll
                for (int rr = 0; rr < 4; ++rr)
                    gs[((mt * 8 + wave) * 16 + quad * 4 + rr) * 17 + l16] = acc[mt][rr];
            __syncthreads();
            #pragma unroll
            for (int mt = 0; mt < 2; ++mt) {
                float gi = gs[((mt * 8 + (j >> 2)) * 16 + m16) * 17 + (j & 3) * 4 + 0] + bf2f(gx4[mt].x);
                float gf = gs[((mt * 8 + (j >> 2)) * 16 + m16) * 17 + (j & 3) * 4 + 1] + bf2f(gx4[mt].y);
                float gg = gs[((mt * 8 + (j >> 2)) * 16 + m16) * 17 + (j & 3) * 4 + 2] + bf2f(gx4[mt].z);
                float go = gs[((mt * 8 + (j >> 2)) * 16 + m16) * 17 + (j & 3) * 4 + 3] + bf2f(gx4[mt].w);
                float si = 1.f / (1.f + __expf(-gi));
                float sf = 1.f / (1.f + __expf(-gf));
                float so = 1.f / (1.f + __expf(-go));
                float tg = tanhf(gg);
                float cn = sf * cst[mt] + si * tg;
                cst[mt] = cn;
                float hn = so * tanhf(cn);
                hstash[(mt * 16 + m16) * 32 + j] = f2bf(hn);
            }
            __syncthreads();
            if (tid < 256) {
                int r = tid >> 3, u = tid & 7;
                unsigned long long val = *(const unsigned long long*)(hstash + r * 32 + u * 4);
                unsigned long long* hwrite = (unsigned long long*)
                    (hcur + ((size_t)(((s + 1) & 1) * 2 + d) * 64 + bh * 32) * 512);
                __hip_atomic_store(hwrite + r * 128 + wc * 8 + u, val,
                                   __ATOMIC_RELAXED, __HIP_MEMORY_SCOPE_AGENT);
                int b = bh * 32 + r;
                bool toS = split && (d ? (t >= 256) : (t < 256));
                if (toS)
                    *(unsigned long long*)(S + ((size_t)t * 64 + b) * 512 + wc * 32 + u * 4) = val;
                else
                    *(unsigned long long*)(hs + ((size_t)t * 64 + b) * 1024 + (size_t)d * 512 + wc * 32 + u * 4) = val;
            }
            __syncthreads();
            if (sl + 1 < kL && tid == 0)
                __hip_atomic_store(flg + wc * 16, (unsigned)(s + 1),
                                   __ATOMIC_RELAXED, __HIP_MEMORY_SCOPE_AGENT);
        }
        #pragma unroll
        for (int mt = 0; mt < 2; ++mt)
            cc[((size_t)d * 64 + bh * 32 + mt * 16 + m16) * 512 + wc * 32 + j] = cst[mt];
    } else {
        // ================= next-chunk GEMM =================
        if (!do_gemm) return;
        const int gw = blockIdx.x - 64;            // 0..191
        const int half = tid >> 8;                 // two 128x128 tiles per WG
        const int tid2 = tid & 255;
        const int w4 = tid2 >> 6;
        const int lane = tid2 & 63;
        const int l16 = lane & 15, quad = lane >> 4;
        unsigned short* As = (unsigned short*)(smem + half * 16384);
        unsigned short* Bs = (unsigned short*)(smem + half * 16384 + 8192);
        const int srw = w4 * 32 + (lane >> 2);
        const int sc  = lane & 3;
        const int wm = w4 >> 1, wn = w4 & 1;
        unsigned short* AsW0 = As + w4 * 1024;
        unsigned short* AsW1 = As + w4 * 1024 + 512;
        unsigned short* BsW0 = Bs + w4 * 1024;
        unsigned short* BsW1 = Bs + w4 * 1024 + 512;
        const int kiters = Kg >> 5;

        for (int pp = gw; pp < 512; pp += 192) {
            const int mb = pp >> 4;
            const int nb = ((pp & 15) << 1) + half;
            const int m0w = mb << 7;
            const int arow0 = (m0w < 2048) ? (gfwd + m0w) : (gbwd + (m0w - 2048));
            const int n0 = nb << 7;
            f32x4 acc[4][4];
            #pragma unroll
            for (int i = 0; i < 4; ++i)
                #pragma unroll
                for (int jj = 0; jj < 4; ++jj) acc[i][jj] = (f32x4){0,0,0,0};
            for (int kk = 0; kk < kiters; ++kk) {
                __syncthreads();               // both halves: same trip counts
                ld_lds16(Ag  + (size_t)(arow0 + srw)      * Kg + kk * 32 + sc * 8, AsW0);
                ld_lds16(Ag  + (size_t)(arow0 + srw + 16) * Kg + kk * 32 + sc * 8, AsW1);
                ld_lds16(Wxg + (size_t)(n0 + srw)         * Kg + kk * 32 + sc * 8, BsW0);
                ld_lds16(Wxg + (size_t)(n0 + srw + 16)    * Kg + kk * 32 + sc * 8, BsW1);
                __syncthreads();
                U16x8 af[4], bf[4];
                #pragma unroll
                for (int i = 0; i < 4; ++i) {
                    af[i].u = *(const uint4*)(As + (wm * 64 + i * 16 + l16) * 32 + quad * 8);
                    bf[i].u = *(const uint4*)(Bs + (wn * 64 + i * 16 + l16) * 32 + quad * 8);
                }
                #pragma unroll
                for (int i = 0; i < 4; ++i)
                    #pragma unroll
                    for (int jj = 0; jj < 4; ++jj)
                        acc[i][jj] = __builtin_amdgcn_mfma_f32_16x16x32_bf16(af[i].v, bf[jj].v, acc[i][jj], 0, 0, 0);
            }
            #pragma unroll
            for (int jj = 0; jj < 4; ++jj) {
                int n = n0 + wn * 64 + jj * 16 + l16;
                float bv = biasg[n];
                #pragma unroll
                for (int i = 0; i < 4; ++i) {
                    int mrow = m0w + wm * 64 + i * 16 + quad * 4;
                    #pragma unroll
                    for (int rr = 0; rr < 4; ++rr)
                        Gxout[(size_t)(mrow + rr) * 4096 + n] = f2bf(acc[i][jj][rr] + bv);
                }
            }
        }
    }
}

// ---------------- final linear, MFMA version ----------------
// grid = 512 (one block per t), block = 256 (4 waves x 16 rows). K=1024 over HS/S halves.
__global__ void k_linear(const unsigned short* __restrict__ hs1,
                         const unsigned short* __restrict__ S,
                         const unsigned short* __restrict__ lwb,   // [16][1024] bf16
                         const float* __restrict__ lb,
                         float* __restrict__ feats) {
    const int t = blockIdx.x;
    const int tid = threadIdx.x;
    const int wave = tid >> 6;
    const int lane = tid & 63;
    const int l16 = lane & 15, quad = lane >> 4;
    __shared__ unsigned short lws[16 * 1032];      // padded stride: 2-way LDS reads
    {
        #pragma unroll
        for (int i = 0; i < 8; ++i) {
            int idx = tid + i * 256;               // uint4 index over 16x1024 shorts
            int n = idx >> 7, c = idx & 127;
            *(uint4*)(lws + n * 1032 + c * 8) = *(const uint4*)(lwb + n * 1024 + c * 8);
        }
    }
    __syncthreads();
    const int brow = wave * 16 + l16;              // batch row this lane's A-frag covers
    f32x4 acc = {0, 0, 0, 0};
    #pragma unroll
    for (int kk = 0; kk < 32; ++kk) {
        int k0 = kk * 32 + quad * 8;
        const unsigned short* p;
        if (kk < 16)   // fwd half: S if t<256 else HS
            p = (t < 256) ? S   + ((size_t)t * 64 + brow) * 512  + k0
                          : hs1 + ((size_t)t * 64 + brow) * 1024 + k0;
        else           // bwd half: S if t>=256 else HS
            p = (t >= 256) ? S   + ((size_t)t * 64 + brow) * 512  + (k0 - 512)
                           : hs1 + ((size_t)t * 64 + brow) * 1024 + k0;
        U16x8 a; a.u = *(const uint4*)p;
        U16x8 b; b.u = *(const uint4*)(lws + l16 * 1032 + k0);
        acc = __builtin_amdgcn_mfma_f32_16x16x32_bf16(a.v, b.v, acc, 0, 0, 0);
    }
    // C[m=quad*4+rr][n=l16]; m -> batch row, n -> class
    float bv = lb[l16];
    #pragma unroll
    for (int rr = 0; rr < 4; ++rr) {
        int b = wave * 16 + quad * 4 + rr;
        feats[(size_t)b * (kT * kC) + t * kC + l16] = acc[rr] + bv;
    }
}

// ---------------- Viterbi ----------------
__global__ void k_viterbi(const float* __restrict__ feats, const float* __restrict__ trans,
                          float* __restrict__ out) {
    int b = blockIdx.x;
    int lane = threadIdx.x;            // block = 64
    __shared__ unsigned char bp[kT * kC];
    __shared__ float fv[2][kC];
    __shared__ float tbuf[kC];
    float trow[16];
    float tstop = 0.f;
    if (lane < 16) {
        #pragma unroll
        for (int p = 0; p < 16; ++p) trow[p] = trans[lane * 16 + p];
        tstop = trans[kSTOP * 16 + lane];
        fv[0][lane] = (lane == kSTART) ? 0.f : NEGV;
    }
    __syncthreads();
    const float* fb = feats + (size_t)b * (kT * kC);
    for (int t = 0; t < kT; ++t) {
        if (lane < 16) {
            float m = -3.4e38f; int arg = 0;
            #pragma unroll
            for (int p = 0; p < 16; ++p) {
                float v = fv[t & 1][p] + trow[p];
                if (v > m) { m = v; arg = p; }   // strict >: first max = jnp.argmax
            }
            bp[t * 16 + lane] = (unsigned char)arg;
            fv[(t + 1) & 1][lane] = m + fb[t * 16 + lane];
        }
        __syncthreads();
    }
    if (lane < 16) tbuf[lane] = fv[kT & 1][lane] + tstop;
    __syncthreads();
    if (lane == 0) {
        float bm = tbuf[0]; int best = 0;
        #pragma unroll
        for (int p = 1; p < 16; ++p) if (tbuf[p] > bm) { bm = tbuf[p]; best = p; }
        out[b] = bm;
        float* path = out + kB + (size_t)b * kT;
        int tag = best;
        for (int t = kT - 1; t >= 0; --t) {
            path[t] = (float)tag;
            tag = bp[t * 16 + tag];
        }
    }
}

// ---------------- host ----------------
extern "C" void kernel_launch(void* const* d_in, const int* in_sizes, int n_in,
                              void* d_out, int out_size, void* d_ws, size_t ws_size,
                              hipStream_t stream) {
    const int*   sent = (const int*)d_in[0];
    const float* emb  = (const float*)d_in[1];
    const float* wih0 = (const float*)d_in[2];
    const float* whh0 = (const float*)d_in[3];
    const float* bih0 = (const float*)d_in[4];
    const float* bhh0 = (const float*)d_in[5];
    const float* wih1 = (const float*)d_in[6];
    const float* whh1 = (const float*)d_in[7];
    const float* bih1 = (const float*)d_in[8];
    const float* bhh1 = (const float*)d_in[9];
    const float* lw   = (const float*)d_in[10];
    const float* lb   = (const float*)d_in[11];
    const float* tr   = (const float*)d_in[12];
    const float* h0   = (const float*)d_in[13];
    const float* c0   = (const float*)d_in[14];
    float* out = (float*)d_out;

    char* ws = (char*)d_ws;
    size_t off = 0;
    auto alloc = [&](size_t bytes) -> void* {
        void* p = ws + off; off += (bytes + 255) & ~(size_t)255; return p;
    };
    // X0 (32MB) + Wx0 dead during layer-1 recurrence; S aliases X0.
    unsigned short* X0    = (unsigned short*)alloc((size_t)kT * kB * 512 * 2);       // 33.5MB
    unsigned short* Wx0   = (unsigned short*)alloc((size_t)4096 * 512 * 2);          // 4MB
    unsigned short* S     = (unsigned short*)X0;                                     // alias
    unsigned short* Wh0   = (unsigned short*)alloc((size_t)4096 * 512 * 2);          // 4MB
    unsigned short* Wx1   = (unsigned short*)alloc((size_t)4096 * 1024 * 2);         // 8MB
    unsigned short* Wh1   = (unsigned short*)alloc((size_t)4096 * 512 * 2);          // 4MB
    float*          biascat0 = (float*)alloc(4096 * 4);
    float*          biascat1 = (float*)alloc(4096 * 4);
    unsigned short* HS    = (unsigned short*)alloc((size_t)kT * kB * 1024 * 2);      // 67MB
    unsigned short* hcur  = (unsigned short*)alloc((size_t)2 * 2 * 2 * kB * kHD * 2);
    float*          ccur  = (float*)alloc((size_t)4 * kB * kHD * 4);
    float*          feats = (float*)alloc((size_t)kB * kT * kC * 4);
    unsigned int*   flags = (unsigned int*)alloc(2048 * 4);
    unsigned short* lwb   = (unsigned short*)alloc(16384 * 2);
    unsigned short* Gx0   = (unsigned short*)alloc((size_t)4096 * 4096 * 2);         // 33.5MB
    unsigned short* Gx1   = (unsigned short*)alloc((size_t)4096 * 4096 * 2);         // 33.5MB
    unsigned short* GxB[2] = {Gx0, Gx1};

    k_castWx<<<4096, 128, 0, stream>>>(wih0, Wx0, 512);
    k_castWx<<<4096, 128, 0, stream>>>(whh0, Wh0, 512);
    k_castWx<<<4096, 128, 0, stream>>>(wih1, Wx1, 1024);
    k_castWx<<<4096, 128, 0, stream>>>(whh1, Wh1, 512);
    k_init<<<(4 * kB * kHD + 8192 + 2048 + 16384 + 255) / 256, 256, 0, stream>>>(
        h0, c0, bih0, bhh0, bih1, bhh1, lw, hcur, ccur, biascat0, biascat1, flags, lwb);
    k_embed<<<kT * kB, 128, 0, stream>>>(sent, emb, X0);

    unsigned short* hcur1 = hcur + (size_t)131072;
    float*          ccur1 = ccur + (size_t)65536;

    // layer 0: lead-in GEMM, then fused rec(ch)+gemm(ch+1)
    k_gemm<<<1024, 256, 0, stream>>>(X0, Wx0, biascat0, Gx0, 512, 0, (kT - kL) * 64);
    for (int ch = 0; ch < 16; ++ch) {
        int s0n = (ch + 1) * kL;
        k_fused<<<256, 512, 0, stream>>>(Wh0, GxB[ch & 1], hcur, ccur, HS, S, flags, ch * kL, 0,
                                         X0, Wx0, biascat0, GxB[(ch + 1) & 1], 512,
                                         s0n * 64, (kT - kL - s0n) * 64, ch < 15);
    }
    // layer 1: lead-in GEMM (after l0 fully done), then fused
    k_gemm<<<1024, 256, 0, stream>>>(HS, Wx1, biascat1, Gx0, 1024, 0, (kT - kL) * 64);
    for (int ch = 0; ch < 16; ++ch) {
        int s0n = (ch + 1) * kL;
        k_fused<<<256, 512, 0, stream>>>(Wh1, GxB[ch & 1], hcur1, ccur1, HS, S, flags + 1024, ch * kL, 1,
                                         HS, Wx1, biascat1, GxB[(ch + 1) & 1], 1024,
                                         s0n * 64, (kT - kL - s0n) * 64, ch < 15);
    }

    k_linear<<<kT, 256, 0, stream>>>(HS, S, lwb, lb, feats);
    k_viterbi<<<kB, 64, 0, stream>>>(feats, tr, out);
}